// Round 2
// baseline (5129.164 us; speedup 1.0000x reference)
//
#include <hip/hip_runtime.h>
#include <hip/hip_bf16.h>

#define B_   8
#define S_   1024
#define D_   512
#define H_   8
#define DK_  64
#define DFF_ 2048

typedef __hip_bfloat16 bf16;

// flag==1 -> data is bf16; flag==0 -> data is fp32
__device__ __forceinline__ float ldmix(const void* p, size_t i, int f) {
    return f ? __bfloat162float(((const bf16*)p)[i]) : ((const float*)p)[i];
}

// ---------------- dtype detection ----------------
// True bf16 tensors (values ~N(0,1)) never have exponent field >= 0xC0.
// fp32 data viewed as uint16 has uniform mantissa halves: ~25% exceed it.
__global__ __launch_bounds__(64) void detect_k(const unsigned short* __restrict__ x,
                                               int* __restrict__ flag)
{
    int cnt = 0;
    for (int i = threadIdx.x; i < 4096; i += 64) {
        int e = (x[i] >> 7) & 0xFF;
        if (e >= 0xC0) cnt++;
    }
#pragma unroll
    for (int off = 32; off; off >>= 1) cnt += __shfl_xor(cnt, off);
    if (threadIdx.x == 0) flag[0] = (cnt > 16) ? 0 : 1;
}

// ---------------- conversion / repack kernels ----------------
__global__ __launch_bounds__(256) void conv_k(const void* __restrict__ in,
                                              float* __restrict__ out, int n,
                                              const int* __restrict__ flag)
{
    int i = blockIdx.x * 256 + threadIdx.x;
    if (i < n) out[i] = ldmix(in, i, flag[0]);
}

// q/k/v weights: in[h, d, k] (H=8, D=512, DK=64) -> out[d, h*64+k]  ([K=512, N=512])
__global__ __launch_bounds__(256) void repack_qkv_k(const void* __restrict__ in,
                                                    float* __restrict__ out,
                                                    const int* __restrict__ flag)
{
    int i = blockIdx.x * 256 + threadIdx.x;      // 0 .. 262143
    int d = i >> 9, n = i & 511;
    int h = n >> 6, k = n & 63;
    out[i] = ldmix(in, (size_t)h * (D_ * DK_) + d * DK_ + k, flag[0]);
}

// transpose+convert: out[c*R + r] = in[r*C + c]   (grid sized exactly R*C/256)
__global__ __launch_bounds__(256) void transpose_k(const void* __restrict__ in,
                                                   float* __restrict__ out, int R, int C,
                                                   const int* __restrict__ flag)
{
    int i = blockIdx.x * 256 + threadIdx.x;
    int r = i / C, c = i % C;
    out[(size_t)c * R + r] = ldmix(in, i, flag[0]);
}

// ---------------- GEMM: C[M,N] = A[M,K] @ W[K,N] + bias (+relu) (+res) ----------------
template <bool HAS_RES, bool RELU>
__global__ __launch_bounds__(256)
void gemm_k(const float* __restrict__ A, const float* __restrict__ W,
            const float* __restrict__ bias, const float* __restrict__ res,
            float* __restrict__ C, int M, int N, int K)
{
    __shared__ float As[64][17];
    __shared__ float Bs[16][64];
    const int tx = threadIdx.x & 15, ty = threadIdx.x >> 4;
    const int row0 = blockIdx.y * 64, col0 = blockIdx.x * 64;
    float acc[4][4] = {};

    for (int k0 = 0; k0 < K; k0 += 16) {
#pragma unroll
        for (int i = 0; i < 4; ++i) {
            int idx = threadIdx.x + i * 256;
            int ar = idx >> 4, ac = idx & 15;
            As[ar][ac] = A[(size_t)(row0 + ar) * K + k0 + ac];
        }
#pragma unroll
        for (int i = 0; i < 4; ++i) {
            int idx = threadIdx.x + i * 256;
            int br = idx >> 6, bc = idx & 63;
            Bs[br][bc] = W[(size_t)(k0 + br) * N + col0 + bc];
        }
        __syncthreads();
#pragma unroll
        for (int kk = 0; kk < 16; ++kk) {
            float a[4], b[4];
#pragma unroll
            for (int i = 0; i < 4; ++i) a[i] = As[ty * 4 + i][kk];
#pragma unroll
            for (int j = 0; j < 4; ++j) b[j] = Bs[kk][tx * 4 + j];
#pragma unroll
            for (int i = 0; i < 4; ++i)
#pragma unroll
                for (int j = 0; j < 4; ++j) acc[i][j] += a[i] * b[j];
        }
        __syncthreads();
    }
#pragma unroll
    for (int i = 0; i < 4; ++i) {
        int m = row0 + ty * 4 + i;
#pragma unroll
        for (int j = 0; j < 4; ++j) {
            int n = col0 + tx * 4 + j;
            float c = acc[i][j] + bias[n];
            if constexpr (RELU) c = fmaxf(c, 0.f);
            if constexpr (HAS_RES) c += res[(size_t)m * N + n];
            C[(size_t)m * N + n] = c;
        }
    }
}

// ---------------- attention: per block 4 query rows of one (b,h) ----------------
__global__ __launch_bounds__(256)
void attn_k(const float* __restrict__ Q, const float* __restrict__ Kb,
            const float* __restrict__ Vb, const int* __restrict__ mask,
            float* __restrict__ O)
{
    const int b = blockIdx.z, h = blockIdx.y, s0 = blockIdx.x << 2;
    const int tid = threadIdx.x;
    const int r = tid >> 6, l = tid & 63;
    __shared__ float qs[4][64];
    __shared__ float Ks[64][65];   // padded: avoids 64-way bank conflict on Ks[l][t]
    __shared__ float sc[4][S_];
    const int bS = b * S_;
    const int hc = h * DK_;

    qs[r][l] = Q[(size_t)(bS + s0 + r) * D_ + hc + l];

    for (int jt = 0; jt < S_; jt += 64) {
        __syncthreads();
#pragma unroll
        for (int i = 0; i < 16; ++i) {
            int idx = tid + i * 256;
            int jr = idx >> 6, jc = idx & 63;
            Ks[jr][jc] = Kb[(size_t)(bS + jt + jr) * D_ + hc + jc];
        }
        __syncthreads();
        float dot = 0.f;
#pragma unroll
        for (int t = 0; t < 64; ++t) dot += qs[r][t] * Ks[l][t];
        float v = dot * 0.125f;                 // 1/sqrt(64)
        if (mask[bS + jt + l] == 0) v = -1e10f;
        sc[r][jt + l] = v;
    }
    __syncthreads();

    // softmax over row r (wave r owns row r)
    float mx = -3e38f;
    for (int j = l; j < S_; j += 64) mx = fmaxf(mx, sc[r][j]);
#pragma unroll
    for (int off = 32; off; off >>= 1) mx = fmaxf(mx, __shfl_xor(mx, off));
    float sum = 0.f;
    for (int j = l; j < S_; j += 64) {
        float e = __expf(sc[r][j] - mx);
        sc[r][j] = e;
        sum += e;
    }
#pragma unroll
    for (int off = 32; off; off >>= 1) sum += __shfl_xor(sum, off);
    const float inv = 1.f / sum;

    // PV: lane l owns output dim l
    const float* vp = Vb + (size_t)bS * D_ + hc + l;
    float o = 0.f;
    for (int j = 0; j < S_; j += 4) {
        o += sc[r][j + 0] * vp[(size_t)(j + 0) * D_];
        o += sc[r][j + 1] * vp[(size_t)(j + 1) * D_];
        o += sc[r][j + 2] * vp[(size_t)(j + 2) * D_];
        o += sc[r][j + 3] * vp[(size_t)(j + 3) * D_];
    }
    O[(size_t)(bS + s0 + r) * D_ + hc + l] = o * inv;
}

// ---------------- LayerNorm over [S,D] per batch ----------------
__global__ __launch_bounds__(256)
void ln_reduce_k(const float* __restrict__ Z, float* __restrict__ stats)
{
    const int b = blockIdx.x >> 7;          // 128 chunks per batch
    const int chunk = blockIdx.x & 127;
    const float* p = Z + (size_t)b * (S_ * D_) + (size_t)chunk * 4096;
    float s = 0.f, s2 = 0.f;
    for (int i = threadIdx.x; i < 4096; i += 256) {
        float v = p[i];
        s += v; s2 += v * v;
    }
#pragma unroll
    for (int off = 32; off; off >>= 1) { s += __shfl_xor(s, off); s2 += __shfl_xor(s2, off); }
    __shared__ float red[8];
    const int w = threadIdx.x >> 6, l = threadIdx.x & 63;
    if (l == 0) { red[w * 2] = s; red[w * 2 + 1] = s2; }
    __syncthreads();
    if (threadIdx.x == 0) {
        atomicAdd(&stats[b * 2],     red[0] + red[2] + red[4] + red[6]);
        atomicAdd(&stats[b * 2 + 1], red[1] + red[3] + red[5] + red[7]);
    }
}

template <bool FINAL>
__global__ __launch_bounds__(256)
void ln_apply_k(const float* __restrict__ Z, const float* __restrict__ stats,
                const void* __restrict__ w, const void* __restrict__ bb,
                void* __restrict__ out, const int* __restrict__ flag)
{
    const int f = flag[0];
    const int b = blockIdx.y;
    const int idx = blockIdx.x * 256 + threadIdx.x;   // 0 .. S*D-1
    const float n = (float)(S_ * D_);
    const float m = stats[b * 2] / n;
    const float var = stats[b * 2 + 1] / n - m * m;
    const float inv = rsqrtf(var + 1e-6f);
    const size_t g = (size_t)b * (S_ * D_) + idx;
    float v = (Z[g] - m) * inv * ldmix(w, idx, f) + ldmix(bb, idx, f);
    if constexpr (FINAL) {
        if (f) ((bf16*)out)[g] = __float2bfloat16(v);
        else   ((float*)out)[g] = v;
    } else {
        ((float*)out)[g] = v;
    }
}

// ---------------- orchestration ----------------
extern "C" void kernel_launch(void* const* d_in, const int* in_sizes, int n_in,
                              void* d_out, int out_size, void* d_ws, size_t ws_size,
                              hipStream_t stream)
{
    (void)in_sizes; (void)n_in; (void)out_size; (void)ws_size;

    const void* x        = d_in[0];
    const void* y        = d_in[1];
    const int*  src_mask = (const int*) d_in[2];
    const int*  trg_mask = (const int*) d_in[3];
    const void* m1_wq = d_in[4];
    const void* m1_bq = d_in[5];
    const void* m1_wk = d_in[6];
    const void* m1_bk = d_in[7];
    const void* m1_wv = d_in[8];
    const void* m1_bv = d_in[9];
    const void* m1_wo = d_in[10];
    const void* m1_bo = d_in[11];
    const void* m2_wq = d_in[12];
    const void* m2_bq = d_in[13];
    const void* m2_wk = d_in[14];
    const void* m2_bk = d_in[15];
    const void* m2_wv = d_in[16];
    const void* m2_bv = d_in[17];
    const void* m2_wo = d_in[18];
    const void* m2_bo = d_in[19];
    const void* pw1   = d_in[20];
    const void* pb1   = d_in[21];
    const void* pw2   = d_in[22];
    const void* pb2   = d_in[23];
    const void* ln1_w = d_in[24];
    const void* ln1_b = d_in[25];
    const void* ln2_w = d_in[26];
    const void* ln2_b = d_in[27];
    const void* ln3_w = d_in[28];
    const void* ln3_b = d_in[29];

    float* ws = (float*)d_ws;
    float* Wq1 = ws;                    // 8 x 262144
    float* Wk1 = Wq1 + 262144;
    float* Wv1 = Wk1 + 262144;
    float* Wo1 = Wv1 + 262144;
    float* Wq2 = Wo1 + 262144;
    float* Wk2 = Wq2 + 262144;
    float* Wv2 = Wk2 + 262144;
    float* Wo2 = Wv2 + 262144;
    float* W1  = Wo2 + 262144;          // [512,2048]
    float* W2  = W1  + 1048576;         // [2048,512]
    float* bcv = W2  + 1048576;         // 8192: converted biases
    float* bq1f = bcv;        float* bk1f = bcv + 512;
    float* bv1f = bcv + 1024; float* bo1f = bcv + 1536;
    float* bq2f = bcv + 2048; float* bk2f = bcv + 2560;
    float* bv2f = bcv + 3072; float* bo2f = bcv + 3584;
    float* pb1f = bcv + 4096;           // 2048
    float* pb2f = bcv + 6144;           // 512
    float* stats = bcv + 8192;          // 64 floats (3 slots x 16)
    int*   flag  = (int*)(stats + 64);  // 16 floats of space
    float* xb  = stats + 80;            // 4M converted x
    float* yb  = xb + 4194304;          // 4M converted y
    float* bufA = yb + 4194304;         // 16M: q|k|v|ao  OR  ff
    float* qb  = bufA;
    float* kb  = qb + 4194304;
    float* vb  = kb + 4194304;
    float* aob = vb + 4194304;
    float* ffb = bufA;                  // overlaps q/k/v/ao (dead during FFN)
    float* x1b = bufA + 16777216;
    float* x2b = x1b + 4194304;
    float* zb  = x2b + 4194304;

    hipMemsetAsync(stats, 0, 64 * sizeof(float), stream);
    detect_k<<<1, 64, 0, stream>>>((const unsigned short*)x, flag);

    // input/weight conversion + repack (runs every call; cheap)
    conv_k<<<16384, 256, 0, stream>>>(x, xb, 4194304, flag);
    conv_k<<<16384, 256, 0, stream>>>(y, yb, 4194304, flag);
    conv_k<<<2, 256, 0, stream>>>(m1_bq, bq1f, 512, flag);
    conv_k<<<2, 256, 0, stream>>>(m1_bk, bk1f, 512, flag);
    conv_k<<<2, 256, 0, stream>>>(m1_bv, bv1f, 512, flag);
    conv_k<<<2, 256, 0, stream>>>(m1_bo, bo1f, 512, flag);
    conv_k<<<2, 256, 0, stream>>>(m2_bq, bq2f, 512, flag);
    conv_k<<<2, 256, 0, stream>>>(m2_bk, bk2f, 512, flag);
    conv_k<<<2, 256, 0, stream>>>(m2_bv, bv2f, 512, flag);
    conv_k<<<2, 256, 0, stream>>>(m2_bo, bo2f, 512, flag);
    conv_k<<<8, 256, 0, stream>>>(pb1, pb1f, 2048, flag);
    conv_k<<<2, 256, 0, stream>>>(pb2, pb2f, 512, flag);

    repack_qkv_k<<<1024, 256, 0, stream>>>(m1_wq, Wq1, flag);
    repack_qkv_k<<<1024, 256, 0, stream>>>(m1_wk, Wk1, flag);
    repack_qkv_k<<<1024, 256, 0, stream>>>(m1_wv, Wv1, flag);
    repack_qkv_k<<<1024, 256, 0, stream>>>(m2_wq, Wq2, flag);
    repack_qkv_k<<<1024, 256, 0, stream>>>(m2_wk, Wk2, flag);
    repack_qkv_k<<<1024, 256, 0, stream>>>(m2_wv, Wv2, flag);
    transpose_k<<<1024, 256, 0, stream>>>(m1_wo, Wo1, 512, 512, flag);
    transpose_k<<<1024, 256, 0, stream>>>(m2_wo, Wo2, 512, 512, flag);
    transpose_k<<<4096, 256, 0, stream>>>(pw1,   W1,  2048, 512, flag);
    transpose_k<<<4096, 256, 0, stream>>>(pw2,   W2,  512, 2048, flag);

    const dim3 blk(256);
    const dim3 g512(512 / 64, 8192 / 64);
    const dim3 g2048(2048 / 64, 8192 / 64);
    const dim3 gat(S_ / 4, H_, B_);
    const dim3 gln(2048, B_);

    // ---- self-attention ----
    gemm_k<false, false><<<g512, blk, 0, stream>>>(xb, Wq1, bq1f, nullptr, qb, 8192, 512, 512);
    gemm_k<false, false><<<g512, blk, 0, stream>>>(xb, Wk1, bk1f, nullptr, kb, 8192, 512, 512);
    gemm_k<false, false><<<g512, blk, 0, stream>>>(xb, Wv1, bv1f, nullptr, vb, 8192, 512, 512);
    attn_k<<<gat, blk, 0, stream>>>(qb, kb, vb, trg_mask, aob);
    gemm_k<true, false><<<g512, blk, 0, stream>>>(aob, Wo1, bo1f, xb, zb, 8192, 512, 512);
    ln_reduce_k<<<1024, blk, 0, stream>>>(zb, stats);
    ln_apply_k<false><<<gln, blk, 0, stream>>>(zb, stats, ln1_w, ln1_b, x1b, flag);

    // ---- cross-attention ----
    gemm_k<false, false><<<g512, blk, 0, stream>>>(x1b, Wq2, bq2f, nullptr, qb, 8192, 512, 512);
    gemm_k<false, false><<<g512, blk, 0, stream>>>(yb, Wk2, bk2f, nullptr, kb, 8192, 512, 512);
    gemm_k<false, false><<<g512, blk, 0, stream>>>(yb, Wv2, bv2f, nullptr, vb, 8192, 512, 512);
    attn_k<<<gat, blk, 0, stream>>>(qb, kb, vb, src_mask, aob);
    gemm_k<true, false><<<g512, blk, 0, stream>>>(aob, Wo2, bo2f, x1b, zb, 8192, 512, 512);
    ln_reduce_k<<<1024, blk, 0, stream>>>(zb, stats + 16);
    ln_apply_k<false><<<gln, blk, 0, stream>>>(zb, stats + 16, ln2_w, ln2_b, x2b, flag);

    // ---- FFN ----
    gemm_k<false, true><<<g2048, blk, 0, stream>>>(x2b, W1, pb1f, nullptr, ffb, 8192, 2048, 512);
    gemm_k<true, false><<<g512, blk, 0, stream>>>(ffb, W2, pb2f, x2b, zb, 8192, 512, 2048);
    ln_reduce_k<<<1024, blk, 0, stream>>>(zb, stats + 32);
    ln_apply_k<true><<<gln, blk, 0, stream>>>(zb, stats + 32, ln3_w, ln3_b, d_out, flag);
}

// Round 3
// 2068.994 us; speedup vs baseline: 2.4791x; 2.4791x over previous
//
#include <hip/hip_runtime.h>
#include <hip/hip_bf16.h>

#define B_   8
#define S_   1024
#define D_   512
#define H_   8
#define DK_  64
#define DFF_ 2048

typedef __hip_bfloat16 bf16;

// flag==1 -> data is bf16; flag==0 -> data is fp32
__device__ __forceinline__ float ldmix(const void* p, size_t i, int f) {
    return f ? __bfloat162float(((const bf16*)p)[i]) : ((const float*)p)[i];
}

// ---------------- dtype detection ----------------
__global__ __launch_bounds__(64) void detect_k(const unsigned short* __restrict__ x,
                                               int* __restrict__ flag)
{
    int cnt = 0;
    for (int i = threadIdx.x; i < 4096; i += 64) {
        int e = (x[i] >> 7) & 0xFF;
        if (e >= 0xC0) cnt++;
    }
#pragma unroll
    for (int off = 32; off; off >>= 1) cnt += __shfl_xor(cnt, off);
    if (threadIdx.x == 0) flag[0] = (cnt > 16) ? 0 : 1;
}

// ---------------- conversion / repack kernels ----------------
__global__ __launch_bounds__(256) void conv_k(const void* __restrict__ in,
                                              float* __restrict__ out, int n,
                                              const int* __restrict__ flag)
{
    int i = blockIdx.x * 256 + threadIdx.x;
    if (i < n) out[i] = ldmix(in, i, flag[0]);
}

// q/k/v weights: in[h, d, k] (H=8, D=512, DK=64) -> out[d, h*64+k]  ([K=512, N=512])
__global__ __launch_bounds__(256) void repack_qkv_k(const void* __restrict__ in,
                                                    float* __restrict__ out,
                                                    const int* __restrict__ flag)
{
    int i = blockIdx.x * 256 + threadIdx.x;      // 0 .. 262143
    int d = i >> 9, n = i & 511;
    int h = n >> 6, k = n & 63;
    out[i] = ldmix(in, (size_t)h * (D_ * DK_) + d * DK_ + k, flag[0]);
}

// transpose+convert: out[c*R + r] = in[r*C + c]
__global__ __launch_bounds__(256) void transpose_k(const void* __restrict__ in,
                                                   float* __restrict__ out, int R, int C,
                                                   const int* __restrict__ flag)
{
    int i = blockIdx.x * 256 + threadIdx.x;
    int r = i / C, c = i % C;
    out[(size_t)c * R + r] = ldmix(in, i, flag[0]);
}

// ---------------- GEMM: C[M,N] = A[M,K] @ W[K,N] + bias (+relu) (+res) ----------------
template <bool HAS_RES, bool RELU>
__global__ __launch_bounds__(256)
void gemm_k(const float* __restrict__ A, const float* __restrict__ W,
            const float* __restrict__ bias, const float* __restrict__ res,
            float* __restrict__ C, int M, int N, int K)
{
    __shared__ float As[64][17];
    __shared__ float Bs[16][64];
    const int tx = threadIdx.x & 15, ty = threadIdx.x >> 4;
    const int row0 = blockIdx.y * 64, col0 = blockIdx.x * 64;
    float acc[4][4] = {};

    for (int k0 = 0; k0 < K; k0 += 16) {
#pragma unroll
        for (int i = 0; i < 4; ++i) {
            int idx = threadIdx.x + i * 256;
            int ar = idx >> 4, ac = idx & 15;
            As[ar][ac] = A[(size_t)(row0 + ar) * K + k0 + ac];
        }
#pragma unroll
        for (int i = 0; i < 4; ++i) {
            int idx = threadIdx.x + i * 256;
            int br = idx >> 6, bc = idx & 63;
            Bs[br][bc] = W[(size_t)(k0 + br) * N + col0 + bc];
        }
        __syncthreads();
#pragma unroll
        for (int kk = 0; kk < 16; ++kk) {
            float a[4], b[4];
#pragma unroll
            for (int i = 0; i < 4; ++i) a[i] = As[ty * 4 + i][kk];
#pragma unroll
            for (int j = 0; j < 4; ++j) b[j] = Bs[kk][tx * 4 + j];
#pragma unroll
            for (int i = 0; i < 4; ++i)
#pragma unroll
                for (int j = 0; j < 4; ++j) acc[i][j] += a[i] * b[j];
        }
        __syncthreads();
    }
#pragma unroll
    for (int i = 0; i < 4; ++i) {
        int m = row0 + ty * 4 + i;
#pragma unroll
        for (int j = 0; j < 4; ++j) {
            int n = col0 + tx * 4 + j;
            float c = acc[i][j] + bias[n];
            if constexpr (RELU) c = fmaxf(c, 0.f);
            if constexpr (HAS_RES) c += res[(size_t)m * N + n];
            C[(size_t)m * N + n] = c;
        }
    }
}

// ---------------- flash attention: 64 query rows of one (b,h) per block ----------------
// 256 threads as 16x16 grid; thread (tx,ty) owns S/P[ty*4+i][tx*4+j] and O[ty*4+i][tx*4+j].
__global__ __launch_bounds__(256)
void fattn_k(const float* __restrict__ Q, const float* __restrict__ Kb,
             const float* __restrict__ Vb, const int* __restrict__ mask,
             float* __restrict__ O)
{
    const int b = blockIdx.z, h = blockIdx.y, s0 = blockIdx.x * 64;
    const int tid = threadIdx.x;
    const int tx = tid & 15, ty = tid >> 4;
    const int bS = b * S_, hc = h * DK_;

    __shared__ float Qs[64][65];    // +1 pad: conflict-free scalar access
    __shared__ float KPs[64][65];   // K-tile, then reused as P-tile
    __shared__ float Vs[64][64];    // flat: float4-friendly rows

    // stage Q tile (rows s0..s0+63 of this head)
#pragma unroll
    for (int i = 0; i < 4; ++i) {
        int idx4 = tid + i * 256;            // 1024 float4s
        int r = idx4 >> 4, c4 = (idx4 & 15) * 4;
        const float4 qv = *reinterpret_cast<const float4*>(
            &Q[(size_t)(bS + s0 + r) * D_ + hc + c4]);
        Qs[r][c4] = qv.x; Qs[r][c4 + 1] = qv.y; Qs[r][c4 + 2] = qv.z; Qs[r][c4 + 3] = qv.w;
    }

    float o[4][4] = {};
    float mrow[4], lrow[4];
#pragma unroll
    for (int i = 0; i < 4; ++i) { mrow[i] = -3.0e38f; lrow[i] = 0.f; }

    for (int t0 = 0; t0 < S_; t0 += 64) {
        __syncthreads();   // prev PV done (and Q staged, first iter)
        // stage K and V tiles
#pragma unroll
        for (int i = 0; i < 4; ++i) {
            int idx4 = tid + i * 256;
            int r = idx4 >> 4, c4 = (idx4 & 15) * 4;
            const float4 kv = *reinterpret_cast<const float4*>(
                &Kb[(size_t)(bS + t0 + r) * D_ + hc + c4]);
            KPs[r][c4] = kv.x; KPs[r][c4 + 1] = kv.y; KPs[r][c4 + 2] = kv.z; KPs[r][c4 + 3] = kv.w;
            const float4 vv = *reinterpret_cast<const float4*>(
                &Vb[(size_t)(bS + t0 + r) * D_ + hc + c4]);
            *reinterpret_cast<float4*>(&Vs[r][c4]) = vv;
        }
        __syncthreads();

        // S = Q K^T  (64x64 over k=64)
        float s[4][4] = {};
#pragma unroll 8
        for (int kk = 0; kk < 64; ++kk) {
            float a[4], bb[4];
#pragma unroll
            for (int i = 0; i < 4; ++i) a[i] = Qs[ty * 4 + i][kk];
#pragma unroll
            for (int j = 0; j < 4; ++j) bb[j] = KPs[tx * 4 + j][kk];
#pragma unroll
            for (int i = 0; i < 4; ++i)
#pragma unroll
                for (int j = 0; j < 4; ++j) s[i][j] += a[i] * bb[j];
        }

        // scale + mask
        const int4 mk = *reinterpret_cast<const int4*>(&mask[bS + t0 + tx * 4]);
        const int mkA[4] = {mk.x, mk.y, mk.z, mk.w};
#pragma unroll
        for (int i = 0; i < 4; ++i)
#pragma unroll
            for (int j = 0; j < 4; ++j)
                s[i][j] = mkA[j] ? s[i][j] * 0.125f : -1.0e10f;

        // online softmax per row (row group = 16 lanes sharing ty)
#pragma unroll
        for (int i = 0; i < 4; ++i) {
            float mx = fmaxf(fmaxf(s[i][0], s[i][1]), fmaxf(s[i][2], s[i][3]));
#pragma unroll
            for (int off = 8; off; off >>= 1) mx = fmaxf(mx, __shfl_xor(mx, off));
            const float mn = fmaxf(mrow[i], mx);
            const float alpha = __expf(mrow[i] - mn);
            mrow[i] = mn;
            float ps = 0.f;
#pragma unroll
            for (int j = 0; j < 4; ++j) {
                const float p = __expf(s[i][j] - mn);
                s[i][j] = p; ps += p;
            }
#pragma unroll
            for (int off = 8; off; off >>= 1) ps += __shfl_xor(ps, off);
            lrow[i] = lrow[i] * alpha + ps;
#pragma unroll
            for (int j = 0; j < 4; ++j) o[i][j] *= alpha;
        }

        __syncthreads();   // everyone done reading K from KPs
        // write P into KPs
#pragma unroll
        for (int i = 0; i < 4; ++i)
#pragma unroll
            for (int j = 0; j < 4; ++j) KPs[ty * 4 + i][tx * 4 + j] = s[i][j];
        __syncthreads();

        // O += P V   (64x64 over k=64)
#pragma unroll 8
        for (int kk = 0; kk < 64; ++kk) {
            float a[4];
#pragma unroll
            for (int i = 0; i < 4; ++i) a[i] = KPs[ty * 4 + i][kk];
            const float4 bv = *reinterpret_cast<const float4*>(&Vs[kk][tx * 4]);
#pragma unroll
            for (int i = 0; i < 4; ++i) {
                o[i][0] += a[i] * bv.x; o[i][1] += a[i] * bv.y;
                o[i][2] += a[i] * bv.z; o[i][3] += a[i] * bv.w;
            }
        }
    }

    // final normalize + write
#pragma unroll
    for (int i = 0; i < 4; ++i) {
        const float invl = 1.0f / lrow[i];
        float4 ov;
        ov.x = o[i][0] * invl; ov.y = o[i][1] * invl;
        ov.z = o[i][2] * invl; ov.w = o[i][3] * invl;
        *reinterpret_cast<float4*>(
            &O[(size_t)(bS + s0 + ty * 4 + i) * D_ + hc + tx * 4]) = ov;
    }
}

// ---------------- LayerNorm over [S,D] per batch ----------------
__global__ __launch_bounds__(256)
void ln_reduce_k(const float* __restrict__ Z, float* __restrict__ stats)
{
    const int b = blockIdx.x >> 7;
    const int chunk = blockIdx.x & 127;
    const float* p = Z + (size_t)b * (S_ * D_) + (size_t)chunk * 4096;
    float s = 0.f, s2 = 0.f;
    for (int i = threadIdx.x; i < 4096; i += 256) {
        float v = p[i];
        s += v; s2 += v * v;
    }
#pragma unroll
    for (int off = 32; off; off >>= 1) { s += __shfl_xor(s, off); s2 += __shfl_xor(s2, off); }
    __shared__ float red[8];
    const int w = threadIdx.x >> 6, l = threadIdx.x & 63;
    if (l == 0) { red[w * 2] = s; red[w * 2 + 1] = s2; }
    __syncthreads();
    if (threadIdx.x == 0) {
        atomicAdd(&stats[b * 2],     red[0] + red[2] + red[4] + red[6]);
        atomicAdd(&stats[b * 2 + 1], red[1] + red[3] + red[5] + red[7]);
    }
}

template <bool FINAL>
__global__ __launch_bounds__(256)
void ln_apply_k(const float* __restrict__ Z, const float* __restrict__ stats,
                const void* __restrict__ w, const void* __restrict__ bb,
                void* __restrict__ out, const int* __restrict__ flag)
{
    const int f = flag[0];
    const int b = blockIdx.y;
    const int idx = blockIdx.x * 256 + threadIdx.x;
    const float n = (float)(S_ * D_);
    const float m = stats[b * 2] / n;
    const float var = stats[b * 2 + 1] / n - m * m;
    const float inv = rsqrtf(var + 1e-6f);
    const size_t g = (size_t)b * (S_ * D_) + idx;
    float v = (Z[g] - m) * inv * ldmix(w, idx, f) + ldmix(bb, idx, f);
    if constexpr (FINAL) {
        if (f) ((bf16*)out)[g] = __float2bfloat16(v);
        else   ((float*)out)[g] = v;
    } else {
        ((float*)out)[g] = v;
    }
}

// ---------------- orchestration ----------------
extern "C" void kernel_launch(void* const* d_in, const int* in_sizes, int n_in,
                              void* d_out, int out_size, void* d_ws, size_t ws_size,
                              hipStream_t stream)
{
    (void)in_sizes; (void)n_in; (void)out_size; (void)ws_size;

    const void* x        = d_in[0];
    const void* y        = d_in[1];
    const int*  src_mask = (const int*) d_in[2];
    const int*  trg_mask = (const int*) d_in[3];
    const void* m1_wq = d_in[4];
    const void* m1_bq = d_in[5];
    const void* m1_wk = d_in[6];
    const void* m1_bk = d_in[7];
    const void* m1_wv = d_in[8];
    const void* m1_bv = d_in[9];
    const void* m1_wo = d_in[10];
    const void* m1_bo = d_in[11];
    const void* m2_wq = d_in[12];
    const void* m2_bq = d_in[13];
    const void* m2_wk = d_in[14];
    const void* m2_bk = d_in[15];
    const void* m2_wv = d_in[16];
    const void* m2_bv = d_in[17];
    const void* m2_wo = d_in[18];
    const void* m2_bo = d_in[19];
    const void* pw1   = d_in[20];
    const void* pb1   = d_in[21];
    const void* pw2   = d_in[22];
    const void* pb2   = d_in[23];
    const void* ln1_w = d_in[24];
    const void* ln1_b = d_in[25];
    const void* ln2_w = d_in[26];
    const void* ln2_b = d_in[27];
    const void* ln3_w = d_in[28];
    const void* ln3_b = d_in[29];

    float* ws = (float*)d_ws;
    float* Wq1 = ws;                    // 8 x 262144
    float* Wk1 = Wq1 + 262144;
    float* Wv1 = Wk1 + 262144;
    float* Wo1 = Wv1 + 262144;
    float* Wq2 = Wo1 + 262144;
    float* Wk2 = Wq2 + 262144;
    float* Wv2 = Wk2 + 262144;
    float* Wo2 = Wv2 + 262144;
    float* W1  = Wo2 + 262144;          // [512,2048]
    float* W2  = W1  + 1048576;         // [2048,512]
    float* bcv = W2  + 1048576;         // converted biases
    float* bq1f = bcv;        float* bk1f = bcv + 512;
    float* bv1f = bcv + 1024; float* bo1f = bcv + 1536;
    float* bq2f = bcv + 2048; float* bk2f = bcv + 2560;
    float* bv2f = bcv + 3072; float* bo2f = bcv + 3584;
    float* pb1f = bcv + 4096;
    float* pb2f = bcv + 6144;
    float* stats = bcv + 8192;
    int*   flag  = (int*)(stats + 64);
    float* xb  = stats + 80;
    float* yb  = xb + 4194304;
    float* bufA = yb + 4194304;
    float* qb  = bufA;
    float* kb  = qb + 4194304;
    float* vb  = kb + 4194304;
    float* aob = vb + 4194304;
    float* ffb = bufA;                  // overlaps q/k/v/ao (dead during FFN)
    float* x1b = bufA + 16777216;
    float* x2b = x1b + 4194304;
    float* zb  = x2b + 4194304;

    hipMemsetAsync(stats, 0, 64 * sizeof(float), stream);
    detect_k<<<1, 64, 0, stream>>>((const unsigned short*)x, flag);

    conv_k<<<16384, 256, 0, stream>>>(x, xb, 4194304, flag);
    conv_k<<<16384, 256, 0, stream>>>(y, yb, 4194304, flag);
    conv_k<<<2, 256, 0, stream>>>(m1_bq, bq1f, 512, flag);
    conv_k<<<2, 256, 0, stream>>>(m1_bk, bk1f, 512, flag);
    conv_k<<<2, 256, 0, stream>>>(m1_bv, bv1f, 512, flag);
    conv_k<<<2, 256, 0, stream>>>(m1_bo, bo1f, 512, flag);
    conv_k<<<2, 256, 0, stream>>>(m2_bq, bq2f, 512, flag);
    conv_k<<<2, 256, 0, stream>>>(m2_bk, bk2f, 512, flag);
    conv_k<<<2, 256, 0, stream>>>(m2_bv, bv2f, 512, flag);
    conv_k<<<2, 256, 0, stream>>>(m2_bo, bo2f, 512, flag);
    conv_k<<<8, 256, 0, stream>>>(pb1, pb1f, 2048, flag);
    conv_k<<<2, 256, 0, stream>>>(pb2, pb2f, 512, flag);

    repack_qkv_k<<<1024, 256, 0, stream>>>(m1_wq, Wq1, flag);
    repack_qkv_k<<<1024, 256, 0, stream>>>(m1_wk, Wk1, flag);
    repack_qkv_k<<<1024, 256, 0, stream>>>(m1_wv, Wv1, flag);
    repack_qkv_k<<<1024, 256, 0, stream>>>(m2_wq, Wq2, flag);
    repack_qkv_k<<<1024, 256, 0, stream>>>(m2_wk, Wk2, flag);
    repack_qkv_k<<<1024, 256, 0, stream>>>(m2_wv, Wv2, flag);
    transpose_k<<<1024, 256, 0, stream>>>(m1_wo, Wo1, 512, 512, flag);
    transpose_k<<<1024, 256, 0, stream>>>(m2_wo, Wo2, 512, 512, flag);
    transpose_k<<<4096, 256, 0, stream>>>(pw1,   W1,  2048, 512, flag);
    transpose_k<<<4096, 256, 0, stream>>>(pw2,   W2,  512, 2048, flag);

    const dim3 blk(256);
    const dim3 g512(512 / 64, 8192 / 64);
    const dim3 g2048(2048 / 64, 8192 / 64);
    const dim3 gfa(S_ / 64, H_, B_);
    const dim3 gln(2048, B_);

    // ---- self-attention ----
    gemm_k<false, false><<<g512, blk, 0, stream>>>(xb, Wq1, bq1f, nullptr, qb, 8192, 512, 512);
    gemm_k<false, false><<<g512, blk, 0, stream>>>(xb, Wk1, bk1f, nullptr, kb, 8192, 512, 512);
    gemm_k<false, false><<<g512, blk, 0, stream>>>(xb, Wv1, bv1f, nullptr, vb, 8192, 512, 512);
    fattn_k<<<gfa, blk, 0, stream>>>(qb, kb, vb, trg_mask, aob);
    gemm_k<true, false><<<g512, blk, 0, stream>>>(aob, Wo1, bo1f, xb, zb, 8192, 512, 512);
    ln_reduce_k<<<1024, blk, 0, stream>>>(zb, stats);
    ln_apply_k<false><<<gln, blk, 0, stream>>>(zb, stats, ln1_w, ln1_b, x1b, flag);

    // ---- cross-attention ----
    gemm_k<false, false><<<g512, blk, 0, stream>>>(x1b, Wq2, bq2f, nullptr, qb, 8192, 512, 512);
    gemm_k<false, false><<<g512, blk, 0, stream>>>(yb, Wk2, bk2f, nullptr, kb, 8192, 512, 512);
    gemm_k<false, false><<<g512, blk, 0, stream>>>(yb, Wv2, bv2f, nullptr, vb, 8192, 512, 512);
    fattn_k<<<gfa, blk, 0, stream>>>(qb, kb, vb, src_mask, aob);
    gemm_k<true, false><<<g512, blk, 0, stream>>>(aob, Wo2, bo2f, x1b, zb, 8192, 512, 512);
    ln_reduce_k<<<1024, blk, 0, stream>>>(zb, stats + 16);
    ln_apply_k<false><<<gln, blk, 0, stream>>>(zb, stats + 16, ln2_w, ln2_b, x2b, flag);

    // ---- FFN ----
    gemm_k<false, true><<<g2048, blk, 0, stream>>>(x2b, W1, pb1f, nullptr, ffb, 8192, 2048, 512);
    gemm_k<true, false><<<g512, blk, 0, stream>>>(ffb, W2, pb2f, x2b, zb, 8192, 512, 2048);
    ln_reduce_k<<<1024, blk, 0, stream>>>(zb, stats + 32);
    ln_apply_k<true><<<gln, blk, 0, stream>>>(zb, stats + 32, ln3_w, ln3_b, d_out, flag);
}

// Round 5
// 1183.342 us; speedup vs baseline: 4.3345x; 1.7484x over previous
//
#include <hip/hip_runtime.h>
#include <hip/hip_bf16.h>

#define B_   8
#define S_   1024
#define D_   512
#define H_   8
#define DK_  64
#define DFF_ 2048

typedef __hip_bfloat16 bf16;
typedef __attribute__((ext_vector_type(8))) short bf16x8;
typedef __attribute__((ext_vector_type(4))) float f32x4;

// flag==1 -> external data is bf16; flag==0 -> fp32
__device__ __forceinline__ float ldmix(const void* p, size_t i, int f) {
    return f ? __bfloat162float(((const bf16*)p)[i]) : ((const float*)p)[i];
}
__device__ __forceinline__ void store_o(float* p, float v) { *p = v; }
__device__ __forceinline__ void store_o(bf16* p, float v)  { *p = __float2bfloat16(v); }

// unpack 8 bf16 (in a uint4) to 8 floats
__device__ __forceinline__ void unpack8(uint4 u, float* p) {
    p[0] = __uint_as_float(u.x << 16); p[1] = __uint_as_float(u.x & 0xffff0000u);
    p[2] = __uint_as_float(u.y << 16); p[3] = __uint_as_float(u.y & 0xffff0000u);
    p[4] = __uint_as_float(u.z << 16); p[5] = __uint_as_float(u.z & 0xffff0000u);
    p[6] = __uint_as_float(u.w << 16); p[7] = __uint_as_float(u.w & 0xffff0000u);
}

// ---------------- dtype detection (proven in R2/R3) ----------------
__global__ __launch_bounds__(64) void detect_k(const unsigned short* __restrict__ x,
                                               int* __restrict__ flag)
{
    int cnt = 0;
    for (int i = threadIdx.x; i < 4096; i += 64) {
        int e = (x[i] >> 7) & 0xFF;
        if (e >= 0xC0) cnt++;
    }
#pragma unroll
    for (int off = 32; off; off >>= 1) cnt += __shfl_xor(cnt, off);
    if (threadIdx.x == 0) flag[0] = (cnt > 16) ? 0 : 1;
}

// ---------------- convert external -> bf16 ----------------
__global__ __launch_bounds__(256) void convb_k(const void* __restrict__ in,
                                               bf16* __restrict__ out, int n,
                                               const int* __restrict__ flag)
{
    const int f = flag[0];
    int i = blockIdx.x * 256 + threadIdx.x;
    if (i < n) out[i] = __float2bfloat16(ldmix(in, i, f));
}

// qkv weights: in[h,d,k] -> out[(h*64+k), d]  ([N][K] bf16)
__global__ __launch_bounds__(256) void repack_qkv_k(const void* __restrict__ in,
                                                    bf16* __restrict__ out,
                                                    const int* __restrict__ flag)
{
    const int f = flag[0];
    int i = blockIdx.x * 256 + threadIdx.x;   // over out
    int n = i >> 9, d = i & 511;
    int h = n >> 6, k = n & 63;
    out[i] = __float2bfloat16(ldmix(in, (size_t)h * (D_ * DK_) + (size_t)d * DK_ + k, f));
}

// ---------------- MFMA GEMM: C[M,N] = A[M,K] @ Wt[N,K]^T + bias (+relu) (+res) ----------------
// BM=128, BN=64, BK=32; 256 thr = 4 waves in 2x2; wave tile 64x32 = 4x2 mfma_16x16x32 accs.
template <bool HAS_RES, bool RELU, typename OutT>
__global__ __launch_bounds__(256)
void mgemm_k(const bf16* __restrict__ A, const bf16* __restrict__ Wt,
             const void* __restrict__ bias, const void* __restrict__ res,
             OutT* __restrict__ C, int M, int N, int K,
             const int* __restrict__ bflag, const int* __restrict__ rflag)
{
    __shared__ bf16 As[128 * 32];
    __shared__ bf16 Bs[64 * 32];
    const int tid = threadIdx.x;
    const int lane = tid & 63, w = tid >> 6;
    const int wr = w >> 1, wc = w & 1;
    const int m0 = blockIdx.y * 128, n0 = blockIdx.x * 64;
    const int l16 = lane & 15, quad = lane >> 4;

    const int sr = tid >> 2;             // staging row 0..63
    const int sc = (tid & 3) * 8;        // staging col (bf16 units)

    const bf16* pa0 = A  + (size_t)(m0 + sr) * K + sc;
    const bf16* pa1 = A  + (size_t)(m0 + 64 + sr) * K + sc;
    const bf16* pb  = Wt + (size_t)(n0 + sr) * K + sc;

    f32x4 acc[4][2];
#pragma unroll
    for (int i = 0; i < 4; ++i)
#pragma unroll
        for (int j = 0; j < 2; ++j) acc[i][j] = (f32x4){0.f, 0.f, 0.f, 0.f};

    for (int k0 = 0; k0 < K; k0 += 32) {
        const uint4 va0 = *(const uint4*)(pa0 + k0);
        const uint4 va1 = *(const uint4*)(pa1 + k0);
        const uint4 vb  = *(const uint4*)(pb  + k0);
        __syncthreads();
        *(uint4*)&As[sr * 32 + sc]        = va0;
        *(uint4*)&As[(64 + sr) * 32 + sc] = va1;
        *(uint4*)&Bs[sr * 32 + sc]        = vb;
        __syncthreads();

        bf16x8 af[4], bg[2];
#pragma unroll
        for (int i = 0; i < 4; ++i)
            af[i] = *(const bf16x8*)&As[(wr * 64 + i * 16 + l16) * 32 + quad * 8];
#pragma unroll
        for (int j = 0; j < 2; ++j)
            bg[j] = *(const bf16x8*)&Bs[(wc * 32 + j * 16 + l16) * 32 + quad * 8];
#pragma unroll
        for (int i = 0; i < 4; ++i)
#pragma unroll
            for (int j = 0; j < 2; ++j)
                acc[i][j] = __builtin_amdgcn_mfma_f32_16x16x32_bf16(af[i], bg[j], acc[i][j], 0, 0, 0);
    }

    const int bf = bflag[0];
    int rf = 0;
    if constexpr (HAS_RES) rf = rflag[0];

    // epilogue: C/D layout col=lane&15, row=quad*4+reg
#pragma unroll
    for (int i = 0; i < 4; ++i) {
        const int row = m0 + wr * 64 + i * 16 + quad * 4;
#pragma unroll
        for (int j = 0; j < 2; ++j) {
            const int col = n0 + wc * 32 + j * 16 + l16;
            const float bv = ldmix(bias, col, bf);
#pragma unroll
            for (int r = 0; r < 4; ++r) {
                float c = acc[i][j][r] + bv;
                if constexpr (RELU) c = fmaxf(c, 0.f);
                if constexpr (HAS_RES) c += ldmix(res, (size_t)(row + r) * N + col, rf);
                store_o(&C[(size_t)(row + r) * N + col], c);
            }
        }
    }
}

// ---------------- flash attention: 64 query rows of one (b,h) per block; bf16 I/O ----------------
__global__ __launch_bounds__(256)
void fattn_k(const bf16* __restrict__ Q, const bf16* __restrict__ Kb,
             const bf16* __restrict__ Vb, const int* __restrict__ mask,
             bf16* __restrict__ O)
{
    const int b = blockIdx.z, h = blockIdx.y, s0 = blockIdx.x * 64;
    const int tid = threadIdx.x;
    const int tx = tid & 15, ty = tid >> 4;
    const int bS = b * S_, hc = h * DK_;

    __shared__ float Qs[64][65];
    __shared__ float KPs[64][65];   // K tile; reused (row-rotated) as P tile
    __shared__ float Vs[64][68];    // stride 68: 16B-aligned rows, conflict-free f4

    const int strow = tid >> 2;
    const int stc0 = (tid & 3) * 8;
    const int stc1 = stc0 + 32;

    {
        const bf16* qp = &Q[(size_t)(bS + s0 + strow) * D_ + hc];
        float f0[8], f1[8];
        unpack8(*(const uint4*)(qp + stc0), f0);
        unpack8(*(const uint4*)(qp + stc1), f1);
#pragma unroll
        for (int k = 0; k < 8; ++k) { Qs[strow][stc0 + k] = f0[k]; Qs[strow][stc1 + k] = f1[k]; }
    }

    float o[4][4] = {};
    float mrow[4], lrow[4];
#pragma unroll
    for (int i = 0; i < 4; ++i) { mrow[i] = -3.0e38f; lrow[i] = 0.f; }

    for (int t0 = 0; t0 < S_; t0 += 64) {
        __syncthreads();
        {
            const bf16* kp = &Kb[(size_t)(bS + t0 + strow) * D_ + hc];
            const bf16* vp = &Vb[(size_t)(bS + t0 + strow) * D_ + hc];
            float f0[8], f1[8], g0[8], g1[8];
            unpack8(*(const uint4*)(kp + stc0), f0);
            unpack8(*(const uint4*)(kp + stc1), f1);
            unpack8(*(const uint4*)(vp + stc0), g0);
            unpack8(*(const uint4*)(vp + stc1), g1);
#pragma unroll
            for (int k = 0; k < 8; ++k) { KPs[strow][stc0 + k] = f0[k]; KPs[strow][stc1 + k] = f1[k]; }
            *(float4*)&Vs[strow][stc0] = *(float4*)&g0[0];
            *(float4*)&Vs[strow][stc0 + 4] = *(float4*)&g0[4];
            *(float4*)&Vs[strow][stc1] = *(float4*)&g1[0];
            *(float4*)&Vs[strow][stc1 + 4] = *(float4*)&g1[4];
        }
        __syncthreads();

        // S = Q K^T
        float s[4][4] = {};
#pragma unroll 8
        for (int kk = 0; kk < 64; ++kk) {
            float a[4], bb[4];
#pragma unroll
            for (int i = 0; i < 4; ++i) a[i] = Qs[ty * 4 + i][kk];
#pragma unroll
            for (int j = 0; j < 4; ++j) bb[j] = KPs[tx * 4 + j][kk];
#pragma unroll
            for (int i = 0; i < 4; ++i)
#pragma unroll
                for (int j = 0; j < 4; ++j) s[i][j] += a[i] * bb[j];
        }

        const int4 mk = *reinterpret_cast<const int4*>(&mask[bS + t0 + tx * 4]);
        const int mkA[4] = {mk.x, mk.y, mk.z, mk.w};
#pragma unroll
        for (int i = 0; i < 4; ++i)
#pragma unroll
            for (int j = 0; j < 4; ++j)
                s[i][j] = mkA[j] ? s[i][j] * 0.125f : -1.0e10f;

#pragma unroll
        for (int i = 0; i < 4; ++i) {
            float mx = fmaxf(fmaxf(s[i][0], s[i][1]), fmaxf(s[i][2], s[i][3]));
#pragma unroll
            for (int off = 8; off; off >>= 1) mx = fmaxf(mx, __shfl_xor(mx, off));
            const float mn = fmaxf(mrow[i], mx);
            const float alpha = __expf(mrow[i] - mn);
            mrow[i] = mn;
            float ps = 0.f;
#pragma unroll
            for (int j = 0; j < 4; ++j) {
                const float p = __expf(s[i][j] - mn);
                s[i][j] = p; ps += p;
            }
#pragma unroll
            for (int off = 8; off; off >>= 1) ps += __shfl_xor(ps, off);
            lrow[i] = lrow[i] * alpha + ps;
#pragma unroll
            for (int j = 0; j < 4; ++j) o[i][j] *= alpha;
        }

        __syncthreads();
        // P row r=ty*4+i stored at 16*i+ty -> write banks 2-way (free)
#pragma unroll
        for (int i = 0; i < 4; ++i)
#pragma unroll
            for (int j = 0; j < 4; ++j) KPs[16 * i + ty][tx * 4 + j] = s[i][j];
        __syncthreads();

#pragma unroll 8
        for (int kk = 0; kk < 64; ++kk) {
            float a[4];
#pragma unroll
            for (int i = 0; i < 4; ++i) a[i] = KPs[16 * i + ty][kk];
            const float4 bv = *reinterpret_cast<const float4*>(&Vs[kk][tx * 4]);
#pragma unroll
            for (int i = 0; i < 4; ++i) {
                o[i][0] += a[i] * bv.x; o[i][1] += a[i] * bv.y;
                o[i][2] += a[i] * bv.z; o[i][3] += a[i] * bv.w;
            }
        }
    }

#pragma unroll
    for (int i = 0; i < 4; ++i) {
        const float invl = 1.0f / lrow[i];
        union { ushort4 u4; unsigned short u[4]; } ov;
#pragma unroll
        for (int j = 0; j < 4; ++j) {
            bf16 t = __float2bfloat16(o[i][j] * invl);
            __builtin_memcpy(&ov.u[j], &t, 2);
        }
        *reinterpret_cast<ushort4*>(
            &O[(size_t)(bS + s0 + ty * 4 + i) * D_ + hc + tx * 4]) = ov.u4;
    }
}

// ---------------- LayerNorm over [S,D] per batch (fp32 Z) ----------------
__global__ __launch_bounds__(256)
void ln_reduce_k(const float* __restrict__ Z, float* __restrict__ stats)
{
    const int b = blockIdx.x >> 7;
    const int chunk = blockIdx.x & 127;
    const float4* p = (const float4*)(Z + (size_t)b * (S_ * D_) + (size_t)chunk * 4096);
    float s = 0.f, s2 = 0.f;
    for (int i = threadIdx.x; i < 1024; i += 256) {
        float4 v = p[i];
        s += v.x + v.y + v.z + v.w;
        s2 += v.x * v.x + v.y * v.y + v.z * v.z + v.w * v.w;
    }
#pragma unroll
    for (int off = 32; off; off >>= 1) { s += __shfl_xor(s, off); s2 += __shfl_xor(s2, off); }
    __shared__ float red[8];
    const int w = threadIdx.x >> 6, l = threadIdx.x & 63;
    if (l == 0) { red[w * 2] = s; red[w * 2 + 1] = s2; }
    __syncthreads();
    if (threadIdx.x == 0) {
        atomicAdd(&stats[b * 2],     red[0] + red[2] + red[4] + red[6]);
        atomicAdd(&stats[b * 2 + 1], red[1] + red[3] + red[5] + red[7]);
    }
}

// non-final: writes fp32 (residual use) + bf16 (GEMM input). final: flag-typed single output.
template <bool FINAL>
__global__ __launch_bounds__(256)
void ln_apply_k(const float* __restrict__ Z, const float* __restrict__ stats,
                const void* __restrict__ w, const void* __restrict__ bb,
                float* __restrict__ outf, bf16* __restrict__ outb,
                void* __restrict__ out_final, const int* __restrict__ flag)
{
    const int f = flag[0];
    const int b = blockIdx.y;
    const int i4 = (blockIdx.x * 256 + threadIdx.x) * 4;   // 0..S*D-1 step 4
    const float n = (float)(S_ * D_);
    const float m = stats[b * 2] / n;
    const float var = stats[b * 2 + 1] / n - m * m;
    const float inv = rsqrtf(var + 1e-6f);
    const size_t g = (size_t)b * (S_ * D_) + i4;
    const float4 z = *(const float4*)&Z[g];
    float v[4];
    v[0] = (z.x - m) * inv * ldmix(w, i4 + 0, f) + ldmix(bb, i4 + 0, f);
    v[1] = (z.y - m) * inv * ldmix(w, i4 + 1, f) + ldmix(bb, i4 + 1, f);
    v[2] = (z.z - m) * inv * ldmix(w, i4 + 2, f) + ldmix(bb, i4 + 2, f);
    v[3] = (z.w - m) * inv * ldmix(w, i4 + 3, f) + ldmix(bb, i4 + 3, f);
    if constexpr (FINAL) {
        if (f) {
            union { ushort4 u4; unsigned short u[4]; } ov;
#pragma unroll
            for (int k = 0; k < 4; ++k) {
                bf16 t = __float2bfloat16(v[k]);
                __builtin_memcpy(&ov.u[k], &t, 2);
            }
            *(ushort4*)&((bf16*)out_final)[g] = ov.u4;
        } else {
            *(float4*)&((float*)out_final)[g] = make_float4(v[0], v[1], v[2], v[3]);
        }
    } else {
        *(float4*)&outf[g] = make_float4(v[0], v[1], v[2], v[3]);
        union { ushort4 u4; unsigned short u[4]; } ov;
#pragma unroll
        for (int k = 0; k < 4; ++k) {
            bf16 t = __float2bfloat16(v[k]);
            __builtin_memcpy(&ov.u[k], &t, 2);
        }
        *(ushort4*)&outb[g] = ov.u4;
    }
}

// ---------------- orchestration ----------------
extern "C" void kernel_launch(void* const* d_in, const int* in_sizes, int n_in,
                              void* d_out, int out_size, void* d_ws, size_t ws_size,
                              hipStream_t stream)
{
    (void)in_sizes; (void)n_in; (void)out_size; (void)ws_size;

    const void* x        = d_in[0];
    const void* y        = d_in[1];
    const int*  src_mask = (const int*) d_in[2];
    const int*  trg_mask = (const int*) d_in[3];
    const void* m1_wq = d_in[4];
    const void* m1_bq = d_in[5];
    const void* m1_wk = d_in[6];
    const void* m1_bk = d_in[7];
    const void* m1_wv = d_in[8];
    const void* m1_bv = d_in[9];
    const void* m1_wo = d_in[10];   // [512,512] = [N][K]
    const void* m1_bo = d_in[11];
    const void* m2_wq = d_in[12];
    const void* m2_bq = d_in[13];
    const void* m2_wk = d_in[14];
    const void* m2_bk = d_in[15];
    const void* m2_wv = d_in[16];
    const void* m2_bv = d_in[17];
    const void* m2_wo = d_in[18];
    const void* m2_bo = d_in[19];
    const void* pw1   = d_in[20];   // [2048,512] = [N][K]
    const void* pb1   = d_in[21];
    const void* pw2   = d_in[22];   // [512,2048] = [N][K]
    const void* pb2   = d_in[23];
    const void* ln1_w = d_in[24];
    const void* ln1_b = d_in[25];
    const void* ln2_w = d_in[26];
    const void* ln2_b = d_in[27];
    const void* ln3_w = d_in[28];
    const void* ln3_b = d_in[29];

    const size_t NACT = (size_t)8192 * 512;      // 4,194,304 elems

    // fp32 region
    float* zb  = (float*)d_ws;                   // residual-sum buffer
    float* x1f = zb  + NACT;
    float* x2f = x1f + NACT;
    float* stats = x2f + NACT;                   // 64 floats
    int*   flag  = (int*)(stats + 64);           // data dtype flag
    int*   zflag = (int*)(stats + 60);           // always 0 (memset)
    // bf16 region
    bf16* xb16 = (bf16*)(stats + 80);
    bf16* yb16 = xb16 + NACT;
    bf16* qb   = yb16 + NACT;
    bf16* kb   = qb   + NACT;
    bf16* vb   = kb   + NACT;
    bf16* aob  = vb   + NACT;
    bf16* x1b  = aob  + NACT;
    bf16* x2b  = x1b  + NACT;
    bf16* ffb  = x2b  + NACT;                    // 8192*2048
    bf16* Wq1r = ffb + (size_t)8192 * 2048;
    bf16* Wk1r = Wq1r + 262144;
    bf16* Wv1r = Wk1r + 262144;
    bf16* Wq2r = Wv1r + 262144;
    bf16* Wk2r = Wq2r + 262144;
    bf16* Wv2r = Wk2r + 262144;
    bf16* Wo1b = Wv2r + 262144;
    bf16* Wo2b = Wo1b + 262144;
    bf16* W1b  = Wo2b + 262144;                  // 1,048,576
    bf16* W2b  = W1b  + 1048576;                 // 1,048,576

    hipMemsetAsync(stats, 0, 80 * sizeof(float), stream);
    detect_k<<<1, 64, 0, stream>>>((const unsigned short*)x, flag);

    // converts (flag-dispatched reads, bf16 writes)
    convb_k<<<16384, 256, 0, stream>>>(x, xb16, (int)NACT, flag);
    convb_k<<<16384, 256, 0, stream>>>(y, yb16, (int)NACT, flag);
    repack_qkv_k<<<1024, 256, 0, stream>>>(m1_wq, Wq1r, flag);
    repack_qkv_k<<<1024, 256, 0, stream>>>(m1_wk, Wk1r, flag);
    repack_qkv_k<<<1024, 256, 0, stream>>>(m1_wv, Wv1r, flag);
    repack_qkv_k<<<1024, 256, 0, stream>>>(m2_wq, Wq2r, flag);
    repack_qkv_k<<<1024, 256, 0, stream>>>(m2_wk, Wk2r, flag);
    repack_qkv_k<<<1024, 256, 0, stream>>>(m2_wv, Wv2r, flag);
    convb_k<<<1024, 256, 0, stream>>>(m1_wo, Wo1b, 262144, flag);
    convb_k<<<1024, 256, 0, stream>>>(m2_wo, Wo2b, 262144, flag);
    convb_k<<<4096, 256, 0, stream>>>(pw1, W1b, 1048576, flag);
    convb_k<<<4096, 256, 0, stream>>>(pw2, W2b, 1048576, flag);

    const dim3 blk(256);
    const dim3 g512(512 / 64, 8192 / 128);       // (8, 64)
    const dim3 g2048(2048 / 64, 8192 / 128);     // (32, 64)
    const dim3 gfa(S_ / 64, H_, B_);
    const dim3 gln(512, B_);

    // ---- self-attention ----
    mgemm_k<false, false, bf16><<<g512, blk, 0, stream>>>(xb16, Wq1r, m1_bq, nullptr, qb, 8192, 512, 512, flag, flag);
    mgemm_k<false, false, bf16><<<g512, blk, 0, stream>>>(xb16, Wk1r, m1_bk, nullptr, kb, 8192, 512, 512, flag, flag);
    mgemm_k<false, false, bf16><<<g512, blk, 0, stream>>>(xb16, Wv1r, m1_bv, nullptr, vb, 8192, 512, 512, flag, flag);
    fattn_k<<<gfa, blk, 0, stream>>>(qb, kb, vb, trg_mask, aob);
    mgemm_k<true, false, float><<<g512, blk, 0, stream>>>(aob, Wo1b, m1_bo, x, zb, 8192, 512, 512, flag, flag);
    ln_reduce_k<<<1024, blk, 0, stream>>>(zb, stats);
    ln_apply_k<false><<<gln, blk, 0, stream>>>(zb, stats, ln1_w, ln1_b, x1f, x1b, nullptr, flag);

    // ---- cross-attention ----
    mgemm_k<false, false, bf16><<<g512, blk, 0, stream>>>(x1b, Wq2r, m2_bq, nullptr, qb, 8192, 512, 512, flag, flag);
    mgemm_k<false, false, bf16><<<g512, blk, 0, stream>>>(yb16, Wk2r, m2_bk, nullptr, kb, 8192, 512, 512, flag, flag);
    mgemm_k<false, false, bf16><<<g512, blk, 0, stream>>>(yb16, Wv2r, m2_bv, nullptr, vb, 8192, 512, 512, flag, flag);
    fattn_k<<<gfa, blk, 0, stream>>>(qb, kb, vb, src_mask, aob);
    mgemm_k<true, false, float><<<g512, blk, 0, stream>>>(aob, Wo2b, m2_bo, x1f, zb, 8192, 512, 512, flag, zflag);
    ln_reduce_k<<<1024, blk, 0, stream>>>(zb, stats + 16);
    ln_apply_k<false><<<gln, blk, 0, stream>>>(zb, stats + 16, ln2_w, ln2_b, x2f, x2b, nullptr, flag);

    // ---- FFN ----
    mgemm_k<false, true, bf16><<<g2048, blk, 0, stream>>>(x2b, W1b, pb1, nullptr, ffb, 8192, 2048, 512, flag, flag);
    mgemm_k<true, false, float><<<g512, blk, 0, stream>>>(ffb, W2b, pb2, x2f, zb, 8192, 512, 2048, flag, zflag);
    ln_reduce_k<<<1024, blk, 0, stream>>>(zb, stats + 32);
    ln_apply_k<true><<<gln, blk, 0, stream>>>(zb, stats + 32, ln3_w, ln3_b, nullptr, nullptr, d_out, flag);
}

// Round 6
// 708.095 us; speedup vs baseline: 7.2436x; 1.6712x over previous
//
#include <hip/hip_runtime.h>
#include <hip/hip_bf16.h>

#define B_   8
#define S_   1024
#define D_   512
#define H_   8
#define DK_  64
#define DFF_ 2048

typedef __hip_bfloat16 bf16;
typedef __attribute__((ext_vector_type(8))) short bf16x8;
typedef __attribute__((ext_vector_type(4))) float f32x4;

// flag==1 -> external data is bf16; flag==0 -> fp32
__device__ __forceinline__ float ldmix(const void* p, size_t i, int f) {
    return f ? __bfloat162float(((const bf16*)p)[i]) : ((const float*)p)[i];
}
__device__ __forceinline__ void store_o(float* p, float v) { *p = v; }
__device__ __forceinline__ void store_o(bf16* p, float v)  { *p = __float2bfloat16(v); }

// ---------------- dtype detection (proven R2/R3/R5) ----------------
__global__ __launch_bounds__(64) void detect_k(const unsigned short* __restrict__ x,
                                               int* __restrict__ flag)
{
    int cnt = 0;
    for (int i = threadIdx.x; i < 4096; i += 64) {
        int e = (x[i] >> 7) & 0xFF;
        if (e >= 0xC0) cnt++;
    }
#pragma unroll
    for (int off = 32; off; off >>= 1) cnt += __shfl_xor(cnt, off);
    if (threadIdx.x == 0) flag[0] = (cnt > 16) ? 0 : 1;
}

// ---------------- convert external -> bf16 ----------------
__global__ __launch_bounds__(256) void convb_k(const void* __restrict__ in,
                                               bf16* __restrict__ out, int n,
                                               const int* __restrict__ flag)
{
    const int f = flag[0];
    int i = blockIdx.x * 256 + threadIdx.x;
    if (i < n) out[i] = __float2bfloat16(ldmix(in, i, f));
}

// qkv weights: in[h,d,k] -> out[(h*64+k), d]  ([N][K] bf16)
__global__ __launch_bounds__(256) void repack_qkv_k(const void* __restrict__ in,
                                                    bf16* __restrict__ out,
                                                    const int* __restrict__ flag)
{
    const int f = flag[0];
    int i = blockIdx.x * 256 + threadIdx.x;
    int n = i >> 9, d = i & 511;
    int h = n >> 6, k = n & 63;
    out[i] = __float2bfloat16(ldmix(in, (size_t)h * (D_ * DK_) + (size_t)d * DK_ + k, f));
}

// ---------------- MFMA GEMM: C[M,N] = A[M,K] @ Wt[N,K]^T + bias (+relu) (+res) ----------------
// BM=128, BN=64, BK=32; 256 thr = 4 waves in 2x2; wave tile 64x32 = 4x2 mfma_16x16x32 accs.
template <bool HAS_RES, bool RELU, typename OutT>
__global__ __launch_bounds__(256)
void mgemm_k(const bf16* __restrict__ A, const bf16* __restrict__ Wt,
             const void* __restrict__ bias, const void* __restrict__ res,
             OutT* __restrict__ C, int M, int N, int K,
             const int* __restrict__ bflag, const int* __restrict__ rflag)
{
    __shared__ bf16 As[128 * 32];
    __shared__ bf16 Bs[64 * 32];
    const int tid = threadIdx.x;
    const int lane = tid & 63, w = tid >> 6;
    const int wr = w >> 1, wc = w & 1;
    const int m0 = blockIdx.y * 128, n0 = blockIdx.x * 64;
    const int l16 = lane & 15, quad = lane >> 4;

    const int sr = tid >> 2;
    const int sc = (tid & 3) * 8;

    const bf16* pa0 = A  + (size_t)(m0 + sr) * K + sc;
    const bf16* pa1 = A  + (size_t)(m0 + 64 + sr) * K + sc;
    const bf16* pb  = Wt + (size_t)(n0 + sr) * K + sc;

    f32x4 acc[4][2];
#pragma unroll
    for (int i = 0; i < 4; ++i)
#pragma unroll
        for (int j = 0; j < 2; ++j) acc[i][j] = (f32x4){0.f, 0.f, 0.f, 0.f};

    for (int k0 = 0; k0 < K; k0 += 32) {
        const uint4 va0 = *(const uint4*)(pa0 + k0);
        const uint4 va1 = *(const uint4*)(pa1 + k0);
        const uint4 vb  = *(const uint4*)(pb  + k0);
        __syncthreads();
        *(uint4*)&As[sr * 32 + sc]        = va0;
        *(uint4*)&As[(64 + sr) * 32 + sc] = va1;
        *(uint4*)&Bs[sr * 32 + sc]        = vb;
        __syncthreads();

        bf16x8 af[4], bg[2];
#pragma unroll
        for (int i = 0; i < 4; ++i)
            af[i] = *(const bf16x8*)&As[(wr * 64 + i * 16 + l16) * 32 + quad * 8];
#pragma unroll
        for (int j = 0; j < 2; ++j)
            bg[j] = *(const bf16x8*)&Bs[(wc * 32 + j * 16 + l16) * 32 + quad * 8];
#pragma unroll
        for (int i = 0; i < 4; ++i)
#pragma unroll
            for (int j = 0; j < 2; ++j)
                acc[i][j] = __builtin_amdgcn_mfma_f32_16x16x32_bf16(af[i], bg[j], acc[i][j], 0, 0, 0);
    }

    const int bf = bflag[0];
    int rf = 0;
    if constexpr (HAS_RES) rf = rflag[0];

#pragma unroll
    for (int i = 0; i < 4; ++i) {
        const int row = m0 + wr * 64 + i * 16 + quad * 4;
#pragma unroll
        for (int j = 0; j < 2; ++j) {
            const int col = n0 + wc * 32 + j * 16 + l16;
            const float bv = ldmix(bias, col, bf);
#pragma unroll
            for (int r = 0; r < 4; ++r) {
                float c = acc[i][j][r] + bv;
                if constexpr (RELU) c = fmaxf(c, 0.f);
                if constexpr (HAS_RES) c += ldmix(res, (size_t)(row + r) * N + col, rf);
                store_o(&C[(size_t)(row + r) * N + col], c);
            }
        }
    }
}

// ---------------- MFMA GEMM with transposed output (V projection) ----------------
// Same compute as mgemm_k; output written as Vt[(b*H+h)][dk][key]  (M=8192, N=512 fixed).
__global__ __launch_bounds__(256)
void mgemmT_k(const bf16* __restrict__ A, const bf16* __restrict__ Wt,
              const void* __restrict__ bias, bf16* __restrict__ C, int K,
              const int* __restrict__ bflag)
{
    const int N = 512;
    __shared__ bf16 As[128 * 32];
    __shared__ bf16 Bs[64 * 32];
    const int tid = threadIdx.x;
    const int lane = tid & 63, w = tid >> 6;
    const int wr = w >> 1, wc = w & 1;
    const int m0 = blockIdx.y * 128, n0 = blockIdx.x * 64;
    const int l16 = lane & 15, quad = lane >> 4;
    const int sr = tid >> 2;
    const int sc = (tid & 3) * 8;

    const bf16* pa0 = A  + (size_t)(m0 + sr) * K + sc;
    const bf16* pa1 = A  + (size_t)(m0 + 64 + sr) * K + sc;
    const bf16* pb  = Wt + (size_t)(n0 + sr) * K + sc;

    f32x4 acc[4][2];
#pragma unroll
    for (int i = 0; i < 4; ++i)
#pragma unroll
        for (int j = 0; j < 2; ++j) acc[i][j] = (f32x4){0.f, 0.f, 0.f, 0.f};

    for (int k0 = 0; k0 < K; k0 += 32) {
        const uint4 va0 = *(const uint4*)(pa0 + k0);
        const uint4 va1 = *(const uint4*)(pa1 + k0);
        const uint4 vb  = *(const uint4*)(pb  + k0);
        __syncthreads();
        *(uint4*)&As[sr * 32 + sc]        = va0;
        *(uint4*)&As[(64 + sr) * 32 + sc] = va1;
        *(uint4*)&Bs[sr * 32 + sc]        = vb;
        __syncthreads();

        bf16x8 af[4], bg[2];
#pragma unroll
        for (int i = 0; i < 4; ++i)
            af[i] = *(const bf16x8*)&As[(wr * 64 + i * 16 + l16) * 32 + quad * 8];
#pragma unroll
        for (int j = 0; j < 2; ++j)
            bg[j] = *(const bf16x8*)&Bs[(wc * 32 + j * 16 + l16) * 32 + quad * 8];
#pragma unroll
        for (int i = 0; i < 4; ++i)
#pragma unroll
            for (int j = 0; j < 2; ++j)
                acc[i][j] = __builtin_amdgcn_mfma_f32_16x16x32_bf16(af[i], bg[j], acc[i][j], 0, 0, 0);
    }

    const int bf = bflag[0];
#pragma unroll
    for (int i = 0; i < 4; ++i) {
        const int row = m0 + wr * 64 + i * 16 + quad * 4;    // b*1024 + key
#pragma unroll
        for (int j = 0; j < 2; ++j) {
            const int col = n0 + wc * 32 + j * 16 + l16;     // h*64 + dk
            const float bv = ldmix(bias, col, bf);
#pragma unroll
            for (int r = 0; r < 4; ++r) {
                const int rr = row + r;
                const int b = rr >> 10, key = rr & 1023;
                // out[((b*8+h)*64+dk)*1024 + key] ; (b*8+h)*64+dk == b*512 + col
                C[((size_t)(b * 512 + col) << 10) | key] = __float2bfloat16(acc[i][j][r] + bv);
            }
        }
    }
}

// ---------------- MFMA flash attention: 64 queries of one (b,h) per block ----------------
// Wave w owns queries 16w..16w+15. K/V tiles of 64 keys. V pre-transposed (Vt[b,h][dk][key]).
__global__ __launch_bounds__(256)
void mfattn_k(const bf16* __restrict__ Q, const bf16* __restrict__ Kb,
              const bf16* __restrict__ Vt, const int* __restrict__ mask,
              bf16* __restrict__ O)
{
    const int b = blockIdx.z, h = blockIdx.y, s0 = blockIdx.x * 64;
    const int tid = threadIdx.x;
    const int lane = tid & 63, w = tid >> 6;
    const int l16 = lane & 15, quad = lane >> 4;
    const int bS = b * S_, hc = h * DK_;
    const size_t vtb = (size_t)(b * H_ + h) * (DK_ * S_);

    __shared__ bf16 Qs[64 * 72];
    __shared__ bf16 Ks[64 * 72];
    __shared__ bf16 Vs[64 * 72];   // [dk][key]
    __shared__ bf16 Ps[64 * 72];   // [query][key]

    const int str = tid >> 3;            // staging row 0..31
    const int stc = (tid & 7) * 8;       // staging col

    *(uint4*)&Qs[str * 72 + stc]        = *(const uint4*)&Q[(size_t)(bS + s0 + str) * D_ + hc + stc];
    *(uint4*)&Qs[(str + 32) * 72 + stc] = *(const uint4*)&Q[(size_t)(bS + s0 + str + 32) * D_ + hc + stc];

    f32x4 acc_o[4];
#pragma unroll
    for (int nb = 0; nb < 4; ++nb) acc_o[nb] = (f32x4){0.f, 0.f, 0.f, 0.f};
    float mrow[4], lrow[4];
#pragma unroll
    for (int r = 0; r < 4; ++r) { mrow[r] = -3.0e38f; lrow[r] = 0.f; }

    for (int t0 = 0; t0 < S_; t0 += 64) {
        __syncthreads();   // prior tile's K/V reads done (also covers Q staging, 1st iter)
        *(uint4*)&Ks[str * 72 + stc]        = *(const uint4*)&Kb[(size_t)(bS + t0 + str) * D_ + hc + stc];
        *(uint4*)&Ks[(str + 32) * 72 + stc] = *(const uint4*)&Kb[(size_t)(bS + t0 + str + 32) * D_ + hc + stc];
        *(uint4*)&Vs[str * 72 + stc]        = *(const uint4*)&Vt[vtb + (size_t)str * S_ + t0 + stc];
        *(uint4*)&Vs[(str + 32) * 72 + stc] = *(const uint4*)&Vt[vtb + (size_t)(str + 32) * S_ + t0 + stc];
        __syncthreads();

        // ---- S = Q K^T ----
        f32x4 sacc[4];
#pragma unroll
        for (int nb = 0; nb < 4; ++nb) sacc[nb] = (f32x4){0.f, 0.f, 0.f, 0.f};
        const bf16x8 aq0 = *(const bf16x8*)&Qs[(w * 16 + l16) * 72 + quad * 8];
        const bf16x8 aq1 = *(const bf16x8*)&Qs[(w * 16 + l16) * 72 + quad * 8 + 32];
#pragma unroll
        for (int nb = 0; nb < 4; ++nb) {
            const bf16x8 b0 = *(const bf16x8*)&Ks[(nb * 16 + l16) * 72 + quad * 8];
            const bf16x8 b1 = *(const bf16x8*)&Ks[(nb * 16 + l16) * 72 + quad * 8 + 32];
            sacc[nb] = __builtin_amdgcn_mfma_f32_16x16x32_bf16(aq0, b0, sacc[nb], 0, 0, 0);
            sacc[nb] = __builtin_amdgcn_mfma_f32_16x16x32_bf16(aq1, b1, sacc[nb], 0, 0, 0);
        }

        // ---- scale + mask ----  (C-layout: col(key)=l16+16nb, row(query)=quad*4+r)
        float s[4][4];   // [nb][r]
#pragma unroll
        for (int nb = 0; nb < 4; ++nb) {
            const int mk = mask[bS + t0 + nb * 16 + l16];
#pragma unroll
            for (int r = 0; r < 4; ++r)
                s[nb][r] = mk ? sacc[nb][r] * 0.125f : -1.0e10f;
        }

        // ---- online softmax per query row (16-lane quad group) ----
#pragma unroll
        for (int r = 0; r < 4; ++r) {
            float mx = fmaxf(fmaxf(s[0][r], s[1][r]), fmaxf(s[2][r], s[3][r]));
#pragma unroll
            for (int off = 8; off; off >>= 1) mx = fmaxf(mx, __shfl_xor(mx, off));
            const float mn = fmaxf(mrow[r], mx);
            const float alpha = __expf(mrow[r] - mn);
            mrow[r] = mn;
            float ps = 0.f;
#pragma unroll
            for (int nb = 0; nb < 4; ++nb) {
                const float p = __expf(s[nb][r] - mn);
                s[nb][r] = p; ps += p;
            }
#pragma unroll
            for (int off = 8; off; off >>= 1) ps += __shfl_xor(ps, off);
            lrow[r] = lrow[r] * alpha + ps;
#pragma unroll
            for (int nb = 0; nb < 4; ++nb) acc_o[nb][r] *= alpha;
        }

        // ---- P -> LDS (bf16), wave-private rows ----
#pragma unroll
        for (int nb = 0; nb < 4; ++nb)
#pragma unroll
            for (int r = 0; r < 4; ++r)
                Ps[(w * 16 + quad * 4 + r) * 72 + nb * 16 + l16] = __float2bfloat16(s[nb][r]);
        __syncthreads();   // conservative: order P writes before A-frag reads

        // ---- O += P V ----
        const bf16x8 ap0 = *(const bf16x8*)&Ps[(w * 16 + l16) * 72 + quad * 8];
        const bf16x8 ap1 = *(const bf16x8*)&Ps[(w * 16 + l16) * 72 + quad * 8 + 32];
#pragma unroll
        for (int nb = 0; nb < 4; ++nb) {
            const bf16x8 v0 = *(const bf16x8*)&Vs[(nb * 16 + l16) * 72 + quad * 8];
            const bf16x8 v1 = *(const bf16x8*)&Vs[(nb * 16 + l16) * 72 + quad * 8 + 32];
            acc_o[nb] = __builtin_amdgcn_mfma_f32_16x16x32_bf16(ap0, v0, acc_o[nb], 0, 0, 0);
            acc_o[nb] = __builtin_amdgcn_mfma_f32_16x16x32_bf16(ap1, v1, acc_o[nb], 0, 0, 0);
        }
    }

    // ---- epilogue: O row=query(quad*4+r +16w), col=dk(l16+16nb) ----
#pragma unroll
    for (int r = 0; r < 4; ++r) {
        const float invl = 1.0f / lrow[r];
        const size_t row = (size_t)(bS + s0 + w * 16 + quad * 4 + r) * D_;
#pragma unroll
        for (int nb = 0; nb < 4; ++nb)
            O[row + hc + nb * 16 + l16] = __float2bfloat16(acc_o[nb][r] * invl);
    }
}

// ---------------- LayerNorm over [S,D] per batch (fp32 Z) ----------------
__global__ __launch_bounds__(256)
void ln_reduce_k(const float* __restrict__ Z, float* __restrict__ stats)
{
    const int b = blockIdx.x >> 7;
    const int chunk = blockIdx.x & 127;
    const float4* p = (const float4*)(Z + (size_t)b * (S_ * D_) + (size_t)chunk * 4096);
    float s = 0.f, s2 = 0.f;
    for (int i = threadIdx.x; i < 1024; i += 256) {
        float4 v = p[i];
        s += v.x + v.y + v.z + v.w;
        s2 += v.x * v.x + v.y * v.y + v.z * v.z + v.w * v.w;
    }
#pragma unroll
    for (int off = 32; off; off >>= 1) { s += __shfl_xor(s, off); s2 += __shfl_xor(s2, off); }
    __shared__ float red[8];
    const int w = threadIdx.x >> 6, l = threadIdx.x & 63;
    if (l == 0) { red[w * 2] = s; red[w * 2 + 1] = s2; }
    __syncthreads();
    if (threadIdx.x == 0) {
        atomicAdd(&stats[b * 2],     red[0] + red[2] + red[4] + red[6]);
        atomicAdd(&stats[b * 2 + 1], red[1] + red[3] + red[5] + red[7]);
    }
}

template <bool FINAL>
__global__ __launch_bounds__(256)
void ln_apply_k(const float* __restrict__ Z, const float* __restrict__ stats,
                const void* __restrict__ w, const void* __restrict__ bb,
                float* __restrict__ outf, bf16* __restrict__ outb,
                void* __restrict__ out_final, const int* __restrict__ flag)
{
    const int f = flag[0];
    const int b = blockIdx.y;
    const int i4 = (blockIdx.x * 256 + threadIdx.x) * 4;
    const float n = (float)(S_ * D_);
    const float m = stats[b * 2] / n;
    const float var = stats[b * 2 + 1] / n - m * m;
    const float inv = rsqrtf(var + 1e-6f);
    const size_t g = (size_t)b * (S_ * D_) + i4;
    const float4 z = *(const float4*)&Z[g];
    float v[4];
    v[0] = (z.x - m) * inv * ldmix(w, i4 + 0, f) + ldmix(bb, i4 + 0, f);
    v[1] = (z.y - m) * inv * ldmix(w, i4 + 1, f) + ldmix(bb, i4 + 1, f);
    v[2] = (z.z - m) * inv * ldmix(w, i4 + 2, f) + ldmix(bb, i4 + 2, f);
    v[3] = (z.w - m) * inv * ldmix(w, i4 + 3, f) + ldmix(bb, i4 + 3, f);
    if constexpr (FINAL) {
        if (f) {
            union { ushort4 u4; unsigned short u[4]; } ov;
#pragma unroll
            for (int k = 0; k < 4; ++k) {
                bf16 t = __float2bfloat16(v[k]);
                __builtin_memcpy(&ov.u[k], &t, 2);
            }
            *(ushort4*)&((bf16*)out_final)[g] = ov.u4;
        } else {
            *(float4*)&((float*)out_final)[g] = make_float4(v[0], v[1], v[2], v[3]);
        }
    } else {
        *(float4*)&outf[g] = make_float4(v[0], v[1], v[2], v[3]);
        union { ushort4 u4; unsigned short u[4]; } ov;
#pragma unroll
        for (int k = 0; k < 4; ++k) {
            bf16 t = __float2bfloat16(v[k]);
            __builtin_memcpy(&ov.u[k], &t, 2);
        }
        *(ushort4*)&outb[g] = ov.u4;
    }
}

// ---------------- orchestration ----------------
extern "C" void kernel_launch(void* const* d_in, const int* in_sizes, int n_in,
                              void* d_out, int out_size, void* d_ws, size_t ws_size,
                              hipStream_t stream)
{
    (void)in_sizes; (void)n_in; (void)out_size; (void)ws_size;

    const void* x        = d_in[0];
    const void* y        = d_in[1];
    const int*  src_mask = (const int*) d_in[2];
    const int*  trg_mask = (const int*) d_in[3];
    const void* m1_wq = d_in[4];
    const void* m1_bq = d_in[5];
    const void* m1_wk = d_in[6];
    const void* m1_bk = d_in[7];
    const void* m1_wv = d_in[8];
    const void* m1_bv = d_in[9];
    const void* m1_wo = d_in[10];
    const void* m1_bo = d_in[11];
    const void* m2_wq = d_in[12];
    const void* m2_bq = d_in[13];
    const void* m2_wk = d_in[14];
    const void* m2_bk = d_in[15];
    const void* m2_wv = d_in[16];
    const void* m2_bv = d_in[17];
    const void* m2_wo = d_in[18];
    const void* m2_bo = d_in[19];
    const void* pw1   = d_in[20];
    const void* pb1   = d_in[21];
    const void* pw2   = d_in[22];
    const void* pb2   = d_in[23];
    const void* ln1_w = d_in[24];
    const void* ln1_b = d_in[25];
    const void* ln2_w = d_in[26];
    const void* ln2_b = d_in[27];
    const void* ln3_w = d_in[28];
    const void* ln3_b = d_in[29];

    const size_t NACT = (size_t)8192 * 512;

    float* zb  = (float*)d_ws;
    float* x1f = zb  + NACT;
    float* x2f = x1f + NACT;
    float* stats = x2f + NACT;                   // 64 floats
    int*   flag  = (int*)(stats + 64);
    int*   zflag = (int*)(stats + 60);           // memset to 0
    bf16* xb16 = (bf16*)(stats + 80);
    bf16* yb16 = xb16 + NACT;
    bf16* qb   = yb16 + NACT;
    bf16* kb   = qb   + NACT;
    bf16* vbT  = kb   + NACT;                    // [b*8+h][dk][key]
    bf16* aob  = vbT  + NACT;
    bf16* x1b  = aob  + NACT;
    bf16* x2b  = x1b  + NACT;
    bf16* ffb  = x2b  + NACT;                    // 8192*2048
    bf16* Wq1r = ffb + (size_t)8192 * 2048;
    bf16* Wk1r = Wq1r + 262144;
    bf16* Wv1r = Wk1r + 262144;
    bf16* Wq2r = Wv1r + 262144;
    bf16* Wk2r = Wq2r + 262144;
    bf16* Wv2r = Wk2r + 262144;
    bf16* Wo1b = Wv2r + 262144;
    bf16* Wo2b = Wo1b + 262144;
    bf16* W1b  = Wo2b + 262144;
    bf16* W2b  = W1b  + 1048576;

    hipMemsetAsync(stats, 0, 80 * sizeof(float), stream);
    detect_k<<<1, 64, 0, stream>>>((const unsigned short*)x, flag);

    convb_k<<<16384, 256, 0, stream>>>(x, xb16, (int)NACT, flag);
    convb_k<<<16384, 256, 0, stream>>>(y, yb16, (int)NACT, flag);
    repack_qkv_k<<<1024, 256, 0, stream>>>(m1_wq, Wq1r, flag);
    repack_qkv_k<<<1024, 256, 0, stream>>>(m1_wk, Wk1r, flag);
    repack_qkv_k<<<1024, 256, 0, stream>>>(m1_wv, Wv1r, flag);
    repack_qkv_k<<<1024, 256, 0, stream>>>(m2_wq, Wq2r, flag);
    repack_qkv_k<<<1024, 256, 0, stream>>>(m2_wk, Wk2r, flag);
    repack_qkv_k<<<1024, 256, 0, stream>>>(m2_wv, Wv2r, flag);
    convb_k<<<1024, 256, 0, stream>>>(m1_wo, Wo1b, 262144, flag);
    convb_k<<<1024, 256, 0, stream>>>(m2_wo, Wo2b, 262144, flag);
    convb_k<<<4096, 256, 0, stream>>>(pw1, W1b, 1048576, flag);
    convb_k<<<4096, 256, 0, stream>>>(pw2, W2b, 1048576, flag);

    const dim3 blk(256);
    const dim3 g512(512 / 64, 8192 / 128);
    const dim3 g2048(2048 / 64, 8192 / 128);
    const dim3 gfa(S_ / 64, H_, B_);
    const dim3 gln(512, B_);

    // ---- self-attention ----
    mgemm_k<false, false, bf16><<<g512, blk, 0, stream>>>(xb16, Wq1r, m1_bq, nullptr, qb, 8192, 512, 512, flag, flag);
    mgemm_k<false, false, bf16><<<g512, blk, 0, stream>>>(xb16, Wk1r, m1_bk, nullptr, kb, 8192, 512, 512, flag, flag);
    mgemmT_k<<<g512, blk, 0, stream>>>(xb16, Wv1r, m1_bv, vbT, 512, flag);
    mfattn_k<<<gfa, blk, 0, stream>>>(qb, kb, vbT, trg_mask, aob);
    mgemm_k<true, false, float><<<g512, blk, 0, stream>>>(aob, Wo1b, m1_bo, x, zb, 8192, 512, 512, flag, flag);
    ln_reduce_k<<<1024, blk, 0, stream>>>(zb, stats);
    ln_apply_k<false><<<gln, blk, 0, stream>>>(zb, stats, ln1_w, ln1_b, x1f, x1b, nullptr, flag);

    // ---- cross-attention ----
    mgemm_k<false, false, bf16><<<g512, blk, 0, stream>>>(x1b, Wq2r, m2_bq, nullptr, qb, 8192, 512, 512, flag, flag);
    mgemm_k<false, false, bf16><<<g512, blk, 0, stream>>>(yb16, Wk2r, m2_bk, nullptr, kb, 8192, 512, 512, flag, flag);
    mgemmT_k<<<g512, blk, 0, stream>>>(yb16, Wv2r, m2_bv, vbT, 512, flag);
    mfattn_k<<<gfa, blk, 0, stream>>>(qb, kb, vbT, src_mask, aob);
    mgemm_k<true, false, float><<<g512, blk, 0, stream>>>(aob, Wo2b, m2_bo, x1f, zb, 8192, 512, 512, flag, zflag);
    ln_reduce_k<<<1024, blk, 0, stream>>>(zb, stats + 16);
    ln_apply_k<false><<<gln, blk, 0, stream>>>(zb, stats + 16, ln2_w, ln2_b, x2f, x2b, nullptr, flag);

    // ---- FFN ----
    mgemm_k<false, true, bf16><<<g2048, blk, 0, stream>>>(x2b, W1b, pb1, nullptr, ffb, 8192, 2048, 512, flag, flag);
    mgemm_k<true, false, float><<<g512, blk, 0, stream>>>(ffb, W2b, pb2, x2f, zb, 8192, 512, 2048, flag, zflag);
    ln_reduce_k<<<1024, blk, 0, stream>>>(zb, stats + 32);
    ln_apply_k<true><<<gln, blk, 0, stream>>>(zb, stats + 32, ln3_w, ln3_b, nullptr, nullptr, d_out, flag);
}

// Round 7
// 635.850 us; speedup vs baseline: 8.0666x; 1.1136x over previous
//
#include <hip/hip_runtime.h>
#include <hip/hip_bf16.h>

#define B_   8
#define S_   1024
#define D_   512
#define H_   8
#define DK_  64
#define DFF_ 2048

typedef __hip_bfloat16 bf16;
typedef __attribute__((ext_vector_type(8))) short bf16x8;
typedef __attribute__((ext_vector_type(4))) float f32x4;

// flag==1 -> bf16 data; flag==0 -> fp32 data
__device__ __forceinline__ float ldmix(const void* p, size_t i, int f) {
    return f ? __bfloat162float(((const bf16*)p)[i]) : ((const float*)p)[i];
}
__device__ __forceinline__ void store_o(float* p, float v) { *p = v; }
__device__ __forceinline__ void store_o(bf16* p, float v)  { *p = __float2bfloat16(v); }

// ---------------- detect dtype + zero LN stats + constants ----------------
__global__ __launch_bounds__(64) void detect_k(const unsigned short* __restrict__ x,
                                               float* __restrict__ stats,
                                               int* __restrict__ flag)
{
    if (threadIdx.x < 48) stats[threadIdx.x] = 0.f;
    int cnt = 0;
    for (int i = threadIdx.x; i < 4096; i += 64) {
        int e = (x[i] >> 7) & 0xFF;
        if (e >= 0xC0) cnt++;
    }
#pragma unroll
    for (int off = 32; off; off >>= 1) cnt += __shfl_xor(cnt, off);
    if (threadIdx.x == 0) { flag[0] = (cnt > 16) ? 0 : 1; flag[1] = 1; }
}

// ---------------- masks -> additive float ----------------
__global__ __launch_bounds__(256) void maskf_k(const int* __restrict__ trg,
                                               const int* __restrict__ src,
                                               float* __restrict__ trgf,
                                               float* __restrict__ srcf)
{
    int i = blockIdx.x * 256 + threadIdx.x;   // 0..16383
    if (i < 8192) trgf[i] = trg[i] ? 0.f : -1.0e10f;
    else          srcf[i - 8192] = src[i - 8192] ? 0.f : -1.0e10f;
}

// ---------------- x,y -> bf16 (one kernel) ----------------
__global__ __launch_bounds__(256) void convxy_k(const void* __restrict__ x,
                                                const void* __restrict__ y,
                                                bf16* __restrict__ xb, bf16* __restrict__ yb,
                                                const int* __restrict__ flag)
{
    const int f = flag[0];
    const int NACT = 8192 * 512;
    int i = blockIdx.x * 256 + threadIdx.x;
    if (i < NACT) xb[i] = __float2bfloat16(ldmix(x, i, f));
    else          yb[i - NACT] = __float2bfloat16(ldmix(y, (size_t)(i - NACT), f));
}

// ---------------- 6 qkv weight repacks: in[h,d,k] -> out[(h*64+k), d] ----------------
__global__ __launch_bounds__(256) void repack6_k(const void* __restrict__ w0, const void* __restrict__ w1,
                                                 const void* __restrict__ w2, const void* __restrict__ w3,
                                                 const void* __restrict__ w4, const void* __restrict__ w5,
                                                 bf16* __restrict__ out, const int* __restrict__ flag)
{
    const int f = flag[0];
    const int widx = blockIdx.x >> 10;                 // 1024 blocks per weight
    const int j = ((blockIdx.x & 1023) << 8) + threadIdx.x;   // 0..262143
    const void* in = widx == 0 ? w0 : widx == 1 ? w1 : widx == 2 ? w2
                   : widx == 3 ? w3 : widx == 4 ? w4 : w5;
    int n = j >> 9, d = j & 511;
    int h = n >> 6, k = n & 63;
    out[(size_t)widx * 262144 + j] =
        __float2bfloat16(ldmix(in, (size_t)h * (D_ * DK_) + (size_t)d * DK_ + k, f));
}

// ---------------- 4 [N][K] weight converts (contiguous out) ----------------
__global__ __launch_bounds__(256) void convw4_k(const void* __restrict__ wo1, const void* __restrict__ wo2,
                                                const void* __restrict__ pw1, const void* __restrict__ pw2,
                                                bf16* __restrict__ out, const int* __restrict__ flag)
{
    const int f = flag[0];
    int i = blockIdx.x * 256 + threadIdx.x;            // 0..2621439
    const void* in; int off;
    if (i < 262144)       { in = wo1; off = 0; }
    else if (i < 524288)  { in = wo2; off = 262144; }
    else if (i < 1572864) { in = pw1; off = 524288; }
    else                  { in = pw2; off = 1572864; }
    out[i] = __float2bfloat16(ldmix(in, (size_t)(i - off), f));
}

// ---------------- MFMA GEMM: C[M,N] = A @ Wt^T + bias (+relu) (+res) ----------------
// BM=128, BN=64, BK=32; 4 waves 2x2; wave 64x32 = 4x2 mfma_16x16x32 accs.
template <bool HAS_RES, bool RELU, typename OutT>
__global__ __launch_bounds__(256)
void mgemm_k(const bf16* __restrict__ A, const bf16* __restrict__ Wt,
             const void* __restrict__ bias, const void* __restrict__ res,
             OutT* __restrict__ C, int M, int N, int K,
             const int* __restrict__ bflag, const int* __restrict__ rflag)
{
    __shared__ bf16 As[128 * 32];
    __shared__ bf16 Bs[64 * 32];
    const int tid = threadIdx.x;
    const int lane = tid & 63, w = tid >> 6;
    const int wr = w >> 1, wc = w & 1;
    const int m0 = blockIdx.y * 128, n0 = blockIdx.x * 64;
    const int l16 = lane & 15, quad = lane >> 4;
    const int sr = tid >> 2, sc = (tid & 3) * 8;

    const bf16* pa0 = A  + (size_t)(m0 + sr) * K + sc;
    const bf16* pa1 = A  + (size_t)(m0 + 64 + sr) * K + sc;
    const bf16* pb  = Wt + (size_t)(n0 + sr) * K + sc;

    f32x4 acc[4][2];
#pragma unroll
    for (int i = 0; i < 4; ++i)
#pragma unroll
        for (int j = 0; j < 2; ++j) acc[i][j] = (f32x4){0.f, 0.f, 0.f, 0.f};

    for (int k0 = 0; k0 < K; k0 += 32) {
        const uint4 va0 = *(const uint4*)(pa0 + k0);
        const uint4 va1 = *(const uint4*)(pa1 + k0);
        const uint4 vb  = *(const uint4*)(pb  + k0);
        __syncthreads();
        *(uint4*)&As[sr * 32 + sc]        = va0;
        *(uint4*)&As[(64 + sr) * 32 + sc] = va1;
        *(uint4*)&Bs[sr * 32 + sc]        = vb;
        __syncthreads();

        bf16x8 af[4], bg[2];
#pragma unroll
        for (int i = 0; i < 4; ++i)
            af[i] = *(const bf16x8*)&As[(wr * 64 + i * 16 + l16) * 32 + quad * 8];
#pragma unroll
        for (int j = 0; j < 2; ++j)
            bg[j] = *(const bf16x8*)&Bs[(wc * 32 + j * 16 + l16) * 32 + quad * 8];
#pragma unroll
        for (int i = 0; i < 4; ++i)
#pragma unroll
            for (int j = 0; j < 2; ++j)
                acc[i][j] = __builtin_amdgcn_mfma_f32_16x16x32_bf16(af[i], bg[j], acc[i][j], 0, 0, 0);
    }

    const int bf = bflag[0];
    int rf = 0;
    if constexpr (HAS_RES) rf = rflag[0];

#pragma unroll
    for (int i = 0; i < 4; ++i) {
        const int row = m0 + wr * 64 + i * 16 + quad * 4;
#pragma unroll
        for (int j = 0; j < 2; ++j) {
            const int col = n0 + wc * 32 + j * 16 + l16;
            const float bv = ldmix(bias, col, bf);
#pragma unroll
            for (int r = 0; r < 4; ++r) {
                float c = acc[i][j][r] + bv;
                if constexpr (RELU) c = fmaxf(c, 0.f);
                if constexpr (HAS_RES) c += ldmix(res, (size_t)(row + r) * N + col, rf);
                store_o(&C[(size_t)(row + r) * N + col], c);
            }
        }
    }
}

// ---------------- fused projection GEMM: routes Q/K/V outputs by 512-col region ----------------
// region 0: qout (scaled 0.125), 1: kout, 2: vtout transposed [b*512+col][key]. K=512, M=8192.
__global__ __launch_bounds__(256)
void mgemm_qkv_k(const bf16* __restrict__ A, const bf16* __restrict__ Wbase,
                 const void* __restrict__ bq, const void* __restrict__ bk, const void* __restrict__ bv,
                 bf16* __restrict__ qout, bf16* __restrict__ kout, bf16* __restrict__ vtout,
                 int roff, const int* __restrict__ bflag)
{
    const int K = 512;
    __shared__ bf16 As[128 * 32];
    __shared__ bf16 Bs[64 * 32];
    const int tid = threadIdx.x;
    const int lane = tid & 63, w = tid >> 6;
    const int wr = w >> 1, wc = w & 1;
    const int m0 = blockIdx.y * 128, n0 = blockIdx.x * 64;
    const int region = roff + (blockIdx.x >> 3);
    const int l16 = lane & 15, quad = lane >> 4;
    const int sr = tid >> 2, sc = (tid & 3) * 8;

    const bf16* pa0 = A     + (size_t)(m0 + sr) * K + sc;
    const bf16* pa1 = A     + (size_t)(m0 + 64 + sr) * K + sc;
    const bf16* pb  = Wbase + (size_t)(n0 + sr) * K + sc;

    f32x4 acc[4][2];
#pragma unroll
    for (int i = 0; i < 4; ++i)
#pragma unroll
        for (int j = 0; j < 2; ++j) acc[i][j] = (f32x4){0.f, 0.f, 0.f, 0.f};

    for (int k0 = 0; k0 < K; k0 += 32) {
        const uint4 va0 = *(const uint4*)(pa0 + k0);
        const uint4 va1 = *(const uint4*)(pa1 + k0);
        const uint4 vb  = *(const uint4*)(pb  + k0);
        __syncthreads();
        *(uint4*)&As[sr * 32 + sc]        = va0;
        *(uint4*)&As[(64 + sr) * 32 + sc] = va1;
        *(uint4*)&Bs[sr * 32 + sc]        = vb;
        __syncthreads();

        bf16x8 af[4], bg[2];
#pragma unroll
        for (int i = 0; i < 4; ++i)
            af[i] = *(const bf16x8*)&As[(wr * 64 + i * 16 + l16) * 32 + quad * 8];
#pragma unroll
        for (int j = 0; j < 2; ++j)
            bg[j] = *(const bf16x8*)&Bs[(wc * 32 + j * 16 + l16) * 32 + quad * 8];
#pragma unroll
        for (int i = 0; i < 4; ++i)
#pragma unroll
            for (int j = 0; j < 2; ++j)
                acc[i][j] = __builtin_amdgcn_mfma_f32_16x16x32_bf16(af[i], bg[j], acc[i][j], 0, 0, 0);
    }

    const int bf = bflag[0];
    const void* bptr = region == 0 ? bq : (region == 1 ? bk : bv);

#pragma unroll
    for (int i = 0; i < 4; ++i) {
        const int row = m0 + wr * 64 + i * 16 + quad * 4;
#pragma unroll
        for (int j = 0; j < 2; ++j) {
            const int col = n0 + wc * 32 + j * 16 + l16;
            const int colr = col & 511;
            const float bvv = ldmix(bptr, colr, bf);
#pragma unroll
            for (int r = 0; r < 4; ++r) {
                const int rr = row + r;
                float c = acc[i][j][r] + bvv;
                if (region == 0) {
                    qout[(size_t)rr * 512 + colr] = __float2bfloat16(c * 0.125f);
                } else if (region == 1) {
                    kout[(size_t)rr * 512 + colr] = __float2bfloat16(c);
                } else {
                    const int b = rr >> 10, key = rr & 1023;
                    vtout[((size_t)(b * 512 + colr) << 10) | key] = __float2bfloat16(c);
                }
            }
        }
    }
}

// ---------------- MFMA flash attention, fixed-max softmax ----------------
// 64 queries of one (b,h) per block; wave w owns queries 16w..16w+15.
// Q pre-scaled by 0.125 at projection; maskf additive {0,-1e10}.
__global__ __launch_bounds__(256)
void mfattn_k(const bf16* __restrict__ Q, const bf16* __restrict__ Kb,
              const bf16* __restrict__ Vt, const float* __restrict__ maskf,
              bf16* __restrict__ O)
{
    const int b = blockIdx.z, h = blockIdx.y, s0 = blockIdx.x * 64;
    const int tid = threadIdx.x;
    const int lane = tid & 63, w = tid >> 6;
    const int l16 = lane & 15, quad = lane >> 4;
    const int bS = b * S_, hc = h * DK_;
    const size_t vtb = (size_t)(b * H_ + h) * (DK_ * S_);

    __shared__ bf16 QPs[64 * 72];  // Q tile, then reused as P tile
    __shared__ bf16 Ks[64 * 72];
    __shared__ bf16 Vs[64 * 72];   // [dk][key]

    const int str = tid >> 3;            // 0..31
    const int stc = (tid & 7) * 8;

    *(uint4*)&QPs[str * 72 + stc]        = *(const uint4*)&Q[(size_t)(bS + s0 + str) * D_ + hc + stc];
    *(uint4*)&QPs[(str + 32) * 72 + stc] = *(const uint4*)&Q[(size_t)(bS + s0 + str + 32) * D_ + hc + stc];
    __syncthreads();

    // Q fragments are loop-invariant: hoist
    const bf16x8 aq0 = *(const bf16x8*)&QPs[(w * 16 + l16) * 72 + quad * 8];
    const bf16x8 aq1 = *(const bf16x8*)&QPs[(w * 16 + l16) * 72 + quad * 8 + 32];

    f32x4 acc_o[4];
#pragma unroll
    for (int nb = 0; nb < 4; ++nb) acc_o[nb] = (f32x4){0.f, 0.f, 0.f, 0.f};
    float lrow[4] = {0.f, 0.f, 0.f, 0.f};

    for (int t0 = 0; t0 < S_; t0 += 64) {
        __syncthreads();   // all waves done reading K/V/P of prior tile (and aq frags, 1st iter)
        *(uint4*)&Ks[str * 72 + stc]        = *(const uint4*)&Kb[(size_t)(bS + t0 + str) * D_ + hc + stc];
        *(uint4*)&Ks[(str + 32) * 72 + stc] = *(const uint4*)&Kb[(size_t)(bS + t0 + str + 32) * D_ + hc + stc];
        *(uint4*)&Vs[str * 72 + stc]        = *(const uint4*)&Vt[vtb + (size_t)str * S_ + t0 + stc];
        *(uint4*)&Vs[(str + 32) * 72 + stc] = *(const uint4*)&Vt[vtb + (size_t)(str + 32) * S_ + t0 + stc];
        __syncthreads();

        // ---- S = Q K^T ----
        f32x4 sacc[4];
#pragma unroll
        for (int nb = 0; nb < 4; ++nb) sacc[nb] = (f32x4){0.f, 0.f, 0.f, 0.f};
#pragma unroll
        for (int nb = 0; nb < 4; ++nb) {
            const bf16x8 b0 = *(const bf16x8*)&Ks[(nb * 16 + l16) * 72 + quad * 8];
            const bf16x8 b1 = *(const bf16x8*)&Ks[(nb * 16 + l16) * 72 + quad * 8 + 32];
            sacc[nb] = __builtin_amdgcn_mfma_f32_16x16x32_bf16(aq0, b0, sacc[nb], 0, 0, 0);
            sacc[nb] = __builtin_amdgcn_mfma_f32_16x16x32_bf16(aq1, b1, sacc[nb], 0, 0, 0);
        }

        // ---- fixed-max softmax: p = exp(s + maskf); accumulate row-sum locally ----
#pragma unroll
        for (int nb = 0; nb < 4; ++nb) {
            const float mv = maskf[bS + t0 + nb * 16 + l16];
#pragma unroll
            for (int r = 0; r < 4; ++r) {
                const float p = __expf(sacc[nb][r] + mv);
                lrow[r] += p;
                // P in C-layout -> LDS (wave-private rows; same-wave RAW handled by lgkmcnt)
                QPs[(w * 16 + quad * 4 + r) * 72 + nb * 16 + l16] = __float2bfloat16(p);
            }
        }

        // ---- O += P V ----
        const bf16x8 ap0 = *(const bf16x8*)&QPs[(w * 16 + l16) * 72 + quad * 8];
        const bf16x8 ap1 = *(const bf16x8*)&QPs[(w * 16 + l16) * 72 + quad * 8 + 32];
#pragma unroll
        for (int nb = 0; nb < 4; ++nb) {
            const bf16x8 v0 = *(const bf16x8*)&Vs[(nb * 16 + l16) * 72 + quad * 8];
            const bf16x8 v1 = *(const bf16x8*)&Vs[(nb * 16 + l16) * 72 + quad * 8 + 32];
            acc_o[nb] = __builtin_amdgcn_mfma_f32_16x16x32_bf16(ap0, v0, acc_o[nb], 0, 0, 0);
            acc_o[nb] = __builtin_amdgcn_mfma_f32_16x16x32_bf16(ap1, v1, acc_o[nb], 0, 0, 0);
        }
    }

    // ---- final: reduce row-sums over the 16-lane group, normalize, store ----
#pragma unroll
    for (int r = 0; r < 4; ++r) {
        float ls = lrow[r];
#pragma unroll
        for (int off = 8; off; off >>= 1) ls += __shfl_xor(ls, off);
        const float invl = 1.0f / ls;
        const size_t row = (size_t)(bS + s0 + w * 16 + quad * 4 + r) * D_;
#pragma unroll
        for (int nb = 0; nb < 4; ++nb)
            O[row + hc + nb * 16 + l16] = __float2bfloat16(acc_o[nb][r] * invl);
    }
}

// ---------------- LayerNorm over [S,D] per batch (fp32 Z) ----------------
__global__ __launch_bounds__(256)
void ln_reduce_k(const float* __restrict__ Z, float* __restrict__ stats)
{
    const int b = blockIdx.x >> 7;
    const int chunk = blockIdx.x & 127;
    const float4* p = (const float4*)(Z + (size_t)b * (S_ * D_) + (size_t)chunk * 4096);
    float s = 0.f, s2 = 0.f;
    for (int i = threadIdx.x; i < 1024; i += 256) {
        float4 v = p[i];
        s += v.x + v.y + v.z + v.w;
        s2 += v.x * v.x + v.y * v.y + v.z * v.z + v.w * v.w;
    }
#pragma unroll
    for (int off = 32; off; off >>= 1) { s += __shfl_xor(s, off); s2 += __shfl_xor(s2, off); }
    __shared__ float red[8];
    const int w = threadIdx.x >> 6, l = threadIdx.x & 63;
    if (l == 0) { red[w * 2] = s; red[w * 2 + 1] = s2; }
    __syncthreads();
    if (threadIdx.x == 0) {
        atomicAdd(&stats[b * 2],     red[0] + red[2] + red[4] + red[6]);
        atomicAdd(&stats[b * 2 + 1], red[1] + red[3] + red[5] + red[7]);
    }
}

template <bool FINAL>
__global__ __launch_bounds__(256)
void ln_apply_k(const float* __restrict__ Z, const float* __restrict__ stats,
                const void* __restrict__ w, const void* __restrict__ bb,
                bf16* __restrict__ outb, void* __restrict__ out_final,
                const int* __restrict__ flag)
{
    const int f = flag[0];
    const int b = blockIdx.y;
    const int i4 = (blockIdx.x * 256 + threadIdx.x) * 4;
    const float n = (float)(S_ * D_);
    const float m = stats[b * 2] / n;
    const float var = stats[b * 2 + 1] / n - m * m;
    const float inv = rsqrtf(var + 1e-6f);
    const size_t g = (size_t)b * (S_ * D_) + i4;
    const float4 z = *(const float4*)&Z[g];
    float v[4];
    v[0] = (z.x - m) * inv * ldmix(w, i4 + 0, f) + ldmix(bb, i4 + 0, f);
    v[1] = (z.y - m) * inv * ldmix(w, i4 + 1, f) + ldmix(bb, i4 + 1, f);
    v[2] = (z.z - m) * inv * ldmix(w, i4 + 2, f) + ldmix(bb, i4 + 2, f);
    v[3] = (z.w - m) * inv * ldmix(w, i4 + 3, f) + ldmix(bb, i4 + 3, f);
    union { ushort4 u4; unsigned short u[4]; } ov;
#pragma unroll
    for (int k = 0; k < 4; ++k) {
        bf16 t = __float2bfloat16(v[k]);
        __builtin_memcpy(&ov.u[k], &t, 2);
    }
    if constexpr (FINAL) {
        if (f) *(ushort4*)&((bf16*)out_final)[g] = ov.u4;
        else   *(float4*)&((float*)out_final)[g] = make_float4(v[0], v[1], v[2], v[3]);
    } else {
        *(ushort4*)&outb[g] = ov.u4;
    }
}

// ---------------- orchestration ----------------
extern "C" void kernel_launch(void* const* d_in, const int* in_sizes, int n_in,
                              void* d_out, int out_size, void* d_ws, size_t ws_size,
                              hipStream_t stream)
{
    (void)in_sizes; (void)n_in; (void)out_size; (void)ws_size;

    const void* x        = d_in[0];
    const void* y        = d_in[1];
    const int*  src_mask = (const int*) d_in[2];
    const int*  trg_mask = (const int*) d_in[3];
    const void* m1_wq = d_in[4];
    const void* m1_bq = d_in[5];
    const void* m1_wk = d_in[6];
    const void* m1_bk = d_in[7];
    const void* m1_wv = d_in[8];
    const void* m1_bv = d_in[9];
    const void* m1_wo = d_in[10];
    const void* m1_bo = d_in[11];
    const void* m2_wq = d_in[12];
    const void* m2_bq = d_in[13];
    const void* m2_wk = d_in[14];
    const void* m2_bk = d_in[15];
    const void* m2_wv = d_in[16];
    const void* m2_bv = d_in[17];
    const void* m2_wo = d_in[18];
    const void* m2_bo = d_in[19];
    const void* pw1   = d_in[20];
    const void* pb1   = d_in[21];
    const void* pw2   = d_in[22];
    const void* pb2   = d_in[23];
    const void* ln1_w = d_in[24];
    const void* ln1_b = d_in[25];
    const void* ln2_w = d_in[26];
    const void* ln2_b = d_in[27];
    const void* ln3_w = d_in[28];
    const void* ln3_b = d_in[29];

    const size_t NACT = (size_t)8192 * 512;

    float* zb    = (float*)d_ws;                 // fp32 residual sum
    float* stats = zb + NACT;                    // 48 floats
    int*   flag  = (int*)(stats + 48);           // [0]=dtype, [1]=1
    float* trgf  = stats + 64;                   // 8192
    float* srcf  = trgf + 8192;                  // 8192
    bf16* xb16 = (bf16*)(srcf + 8192);
    bf16* yb16 = xb16 + NACT;
    bf16* qb   = yb16 + NACT;
    bf16* kb   = qb   + NACT;
    bf16* vbT  = kb   + NACT;                    // [b*8+h][dk][key]
    bf16* aob  = vbT  + NACT;
    bf16* x1b  = aob  + NACT;
    bf16* x2b  = x1b  + NACT;
    bf16* ffb  = x2b  + NACT;                    // 8192*2048
    bf16* Wq1r = ffb  + (size_t)8192 * 2048;     // 6 qkv repacks contiguous
    bf16* Wk2r = Wq1r + 3 * 262144;              // (q1,k1,v1) then (q2,k2,v2)
    bf16* Wq2r = Wq1r + 3 * 262144;
    bf16* Wo1b = Wq1r + 6 * 262144;              // 4 converts contiguous
    bf16* Wo2b = Wo1b + 262144;
    bf16* W1b  = Wo2b + 262144;
    bf16* W2b  = W1b  + 1048576;
    (void)Wk2r;

    detect_k<<<1, 64, 0, stream>>>((const unsigned short*)x, stats, flag);
    maskf_k<<<64, 256, 0, stream>>>(trg_mask, src_mask, trgf, srcf);
    convxy_k<<<32768, 256, 0, stream>>>(x, y, xb16, yb16, flag);
    repack6_k<<<6144, 256, 0, stream>>>(m1_wq, m1_wk, m1_wv, m2_wq, m2_wk, m2_wv, Wq1r, flag);
    convw4_k<<<10240, 256, 0, stream>>>(m1_wo, m2_wo, pw1, pw2, Wo1b, flag);

    const dim3 blk(256);
    const dim3 gqkv(24, 64);
    const dim3 gq(8, 64);
    const dim3 gkv(16, 64);
    const dim3 g512(8, 64);
    const dim3 g2048(32, 64);
    const dim3 gfa(S_ / 64, H_, B_);
    const dim3 gln(512, B_);

    // ---- self-attention ----
    mgemm_qkv_k<<<gqkv, blk, 0, stream>>>(xb16, Wq1r, m1_bq, m1_bk, m1_bv, qb, kb, vbT, 0, flag);
    mfattn_k<<<gfa, blk, 0, stream>>>(qb, kb, vbT, trgf, aob);
    mgemm_k<true, false, float><<<g512, blk, 0, stream>>>(aob, Wo1b, m1_bo, x, zb, 8192, 512, 512, flag, flag);
    ln_reduce_k<<<1024, blk, 0, stream>>>(zb, stats);
    ln_apply_k<false><<<gln, blk, 0, stream>>>(zb, stats, ln1_w, ln1_b, x1b, nullptr, flag);

    // ---- cross-attention ----
    mgemm_qkv_k<<<gq, blk, 0, stream>>>(x1b, Wq2r, m2_bq, m2_bk, m2_bv, qb, kb, vbT, 0, flag);
    mgemm_qkv_k<<<gkv, blk, 0, stream>>>(yb16, Wq2r + 262144, m2_bq, m2_bk, m2_bv, qb, kb, vbT, 1, flag);
    mfattn_k<<<gfa, blk, 0, stream>>>(qb, kb, vbT, srcf, aob);
    mgemm_k<true, false, float><<<g512, blk, 0, stream>>>(aob, Wo2b, m2_bo, x1b, zb, 8192, 512, 512, flag, flag + 1);
    ln_reduce_k<<<1024, blk, 0, stream>>>(zb, stats + 16);
    ln_apply_k<false><<<gln, blk, 0, stream>>>(zb, stats + 16, ln2_w, ln2_b, x2b, nullptr, flag);

    // ---- FFN ----
    mgemm_k<false, true, bf16><<<g2048, blk, 0, stream>>>(x2b, W1b, pb1, nullptr, ffb, 8192, 2048, 512, flag, flag);
    mgemm_k<true, false, float><<<g512, blk, 0, stream>>>(ffb, W2b, pb2, x2b, zb, 8192, 512, 2048, flag, flag + 1);
    ln_reduce_k<<<1024, blk, 0, stream>>>(zb, stats + 32);
    ln_apply_k<true><<<gln, blk, 0, stream>>>(zb, stats + 32, ln3_w, ln3_b, nullptr, d_out, flag);
}

// Round 8
// 623.093 us; speedup vs baseline: 8.2318x; 1.0205x over previous
//
#include <hip/hip_runtime.h>
#include <hip/hip_bf16.h>

#define B_   8
#define S_   1024
#define D_   512
#define H_   8
#define DK_  64
#define DFF_ 2048

typedef __hip_bfloat16 bf16;
typedef __attribute__((ext_vector_type(8))) short bf16x8;
typedef __attribute__((ext_vector_type(4))) float f32x4;

// flag==1 -> bf16 data; flag==0 -> fp32 data
__device__ __forceinline__ float ldmix(const void* p, size_t i, int f) {
    return f ? __bfloat162float(((const bf16*)p)[i]) : ((const float*)p)[i];
}
__device__ __forceinline__ void store_o(float* p, float v) { *p = v; }
__device__ __forceinline__ void store_o(bf16* p, float v)  { *p = __float2bfloat16(v); }

// async global->LDS, 16B per lane; lds base must be wave-uniform (lane*16 implicit)
__device__ __forceinline__ void gl_lds16(const void* g, void* l) {
    __builtin_amdgcn_global_load_lds(
        (const __attribute__((address_space(1))) unsigned int*)g,
        (__attribute__((address_space(3))) unsigned int*)l, 16, 0, 0);
}

// ---------------- detect dtype + zero LN stats + constants ----------------
__global__ __launch_bounds__(64) void detect_k(const unsigned short* __restrict__ x,
                                               float* __restrict__ stats,
                                               int* __restrict__ flag)
{
    if (threadIdx.x < 48) stats[threadIdx.x] = 0.f;
    int cnt = 0;
    for (int i = threadIdx.x; i < 4096; i += 64) {
        int e = (x[i] >> 7) & 0xFF;
        if (e >= 0xC0) cnt++;
    }
#pragma unroll
    for (int off = 32; off; off >>= 1) cnt += __shfl_xor(cnt, off);
    if (threadIdx.x == 0) { flag[0] = (cnt > 16) ? 0 : 1; flag[1] = 1; }
}

// ---------------- masks -> additive float ----------------
__global__ __launch_bounds__(256) void maskf_k(const int* __restrict__ trg,
                                               const int* __restrict__ src,
                                               float* __restrict__ trgf,
                                               float* __restrict__ srcf)
{
    int i = blockIdx.x * 256 + threadIdx.x;
    if (i < 8192) trgf[i] = trg[i] ? 0.f : -1.0e10f;
    else          srcf[i - 8192] = src[i - 8192] ? 0.f : -1.0e10f;
}

// ---------------- x,y -> bf16 ----------------
__global__ __launch_bounds__(256) void convxy_k(const void* __restrict__ x,
                                                const void* __restrict__ y,
                                                bf16* __restrict__ xb, bf16* __restrict__ yb,
                                                const int* __restrict__ flag)
{
    const int f = flag[0];
    const int NACT = 8192 * 512;
    int i = blockIdx.x * 256 + threadIdx.x;
    if (i < NACT) xb[i] = __float2bfloat16(ldmix(x, i, f));
    else          yb[i - NACT] = __float2bfloat16(ldmix(y, (size_t)(i - NACT), f));
}

// ---------------- 6 qkv weight repacks: in[h,d,k] -> out[(h*64+k), d] ----------------
__global__ __launch_bounds__(256) void repack6_k(const void* __restrict__ w0, const void* __restrict__ w1,
                                                 const void* __restrict__ w2, const void* __restrict__ w3,
                                                 const void* __restrict__ w4, const void* __restrict__ w5,
                                                 bf16* __restrict__ out, const int* __restrict__ flag)
{
    const int f = flag[0];
    const int widx = blockIdx.x >> 10;
    const int j = ((blockIdx.x & 1023) << 8) + threadIdx.x;
    const void* in = widx == 0 ? w0 : widx == 1 ? w1 : widx == 2 ? w2
                   : widx == 3 ? w3 : widx == 4 ? w4 : w5;
    int n = j >> 9, d = j & 511;
    int h = n >> 6, k = n & 63;
    out[(size_t)widx * 262144 + j] =
        __float2bfloat16(ldmix(in, (size_t)h * (D_ * DK_) + (size_t)d * DK_ + k, f));
}

// ---------------- 4 [N][K] weight converts ----------------
__global__ __launch_bounds__(256) void convw4_k(const void* __restrict__ wo1, const void* __restrict__ wo2,
                                                const void* __restrict__ pw1, const void* __restrict__ pw2,
                                                bf16* __restrict__ out, const int* __restrict__ flag)
{
    const int f = flag[0];
    int i = blockIdx.x * 256 + threadIdx.x;
    const void* in; int off;
    if (i < 262144)       { in = wo1; off = 0; }
    else if (i < 524288)  { in = wo2; off = 262144; }
    else if (i < 1572864) { in = pw1; off = 524288; }
    else                  { in = pw2; off = 1572864; }
    out[i] = __float2bfloat16(ldmix(in, (size_t)(i - off), f));
}

// ==================== m97-style MFMA GEMM core ====================
// BM=128, BN=128, BK=32; 4 waves 2x2, wave tile 64x64 (4x4 mfma_16x16x32 accs).
// global_load_lds 16B staging into XOR-swizzled LDS (granule p = q ^ ((row>>1)&3)).
// 1-D grid with XCD-stripe mapping: xcd=lin&7 owns M-stripe, N fastest within.
// Gy = M/128 = 64 (fixed). Epilogue is a template-hook lambda-free switch.

#define GEMM_CORE(APTR, WPTR, KDIM, M0OUT, N0OUT)                                   \
    __shared__ bf16 As[4096];                                                       \
    __shared__ bf16 Bs[4096];                                                       \
    const int tid = threadIdx.x;                                                    \
    const int lane = tid & 63, w = tid >> 6;                                        \
    const int wr = w >> 1, wc = w & 1;                                              \
    const int l16 = lane & 15, quad = lane >> 4;                                    \
    const int lin = blockIdx.x;                                                     \
    const int mt = (lin & 7) * 8 + (lin >> 3) / Gx;                                 \
    const int nt = (lin >> 3) % Gx;                                                 \
    const int M0OUT = mt * 128, N0OUT = nt * 128;                                   \
    const int r0 = tid >> 2;                                                        \
    const int g0 = (tid & 3) ^ ((r0 >> 1) & 3);                                     \
    const bf16* pa0 = (APTR) + (size_t)(M0OUT + r0) * (KDIM) + g0 * 8;              \
    const bf16* pa1 = pa0 + (size_t)64 * (KDIM);                                    \
    const bf16* pb0 = (WPTR) + (size_t)(N0OUT + r0) * (KDIM) + g0 * 8;              \
    const bf16* pb1 = pb0 + (size_t)64 * (KDIM);                                    \
    bf16* lA0 = As + w * 512;  bf16* lA1 = As + 2048 + w * 512;                     \
    bf16* lB0 = Bs + w * 512;  bf16* lB1 = Bs + 2048 + w * 512;                     \
    f32x4 acc[4][4];                                                                \
    _Pragma("unroll") for (int i = 0; i < 4; ++i)                                   \
    _Pragma("unroll") for (int j = 0; j < 4; ++j)                                   \
        acc[i][j] = (f32x4){0.f, 0.f, 0.f, 0.f};                                    \
    int aoff[4], boff[4];                                                           \
    _Pragma("unroll") for (int i = 0; i < 4; ++i) {                                 \
        const int ra = wr * 64 + i * 16 + l16;                                      \
        aoff[i] = ra * 32 + (quad ^ ((ra >> 1) & 3)) * 8;                           \
        const int rb = wc * 64 + i * 16 + l16;                                      \
        boff[i] = rb * 32 + (quad ^ ((rb >> 1) & 3)) * 8;                           \
    }                                                                               \
    for (int k0 = 0; k0 < (KDIM); k0 += 32) {                                       \
        __syncthreads();                                                            \
        gl_lds16(pa0 + k0, lA0);                                                    \
        gl_lds16(pa1 + k0, lA1);                                                    \
        gl_lds16(pb0 + k0, lB0);                                                    \
        gl_lds16(pb1 + k0, lB1);                                                    \
        __syncthreads();                                                            \
        bf16x8 af[4], bg[4];                                                        \
        _Pragma("unroll") for (int i = 0; i < 4; ++i) af[i] = *(const bf16x8*)&As[aoff[i]]; \
        _Pragma("unroll") for (int j = 0; j < 4; ++j) bg[j] = *(const bf16x8*)&Bs[boff[j]]; \
        _Pragma("unroll") for (int i = 0; i < 4; ++i)                               \
        _Pragma("unroll") for (int j = 0; j < 4; ++j)                               \
            acc[i][j] = __builtin_amdgcn_mfma_f32_16x16x32_bf16(af[i], bg[j], acc[i][j], 0, 0, 0); \
    }

// standard GEMM: C[M,N] = A @ Wt^T + bias (+relu) (+res)
template <bool HAS_RES, bool RELU, typename OutT>
__global__ __launch_bounds__(256)
void mgemm_k(const bf16* __restrict__ A, const bf16* __restrict__ Wt,
             const void* __restrict__ bias, const void* __restrict__ res,
             OutT* __restrict__ C, int N, int K, int Gx,
             const int* __restrict__ bflag, const int* __restrict__ rflag)
{
    GEMM_CORE(A, Wt, K, m0, n0)
    const int bf = bflag[0];
    int rf = 0;
    if constexpr (HAS_RES) rf = rflag[0];
#pragma unroll
    for (int i = 0; i < 4; ++i) {
        const int row = m0 + wr * 64 + i * 16 + quad * 4;
#pragma unroll
        for (int j = 0; j < 4; ++j) {
            const int col = n0 + wc * 64 + j * 16 + l16;
            const float bv = ldmix(bias, col, bf);
#pragma unroll
            for (int r = 0; r < 4; ++r) {
                float c = acc[i][j][r] + bv;
                if constexpr (RELU) c = fmaxf(c, 0.f);
                if constexpr (HAS_RES) c += ldmix(res, (size_t)(row + r) * N + col, rf);
                store_o(&C[(size_t)(row + r) * N + col], c);
            }
        }
    }
}

// fused projection GEMM: routes Q (x0.125) / K / V(transposed) by 512-col region
__global__ __launch_bounds__(256)
void mgemm_qkv_k(const bf16* __restrict__ A, const bf16* __restrict__ Wbase,
                 const void* __restrict__ bq, const void* __restrict__ bk, const void* __restrict__ bv,
                 bf16* __restrict__ qout, bf16* __restrict__ kout, bf16* __restrict__ vtout,
                 int Gx, int roff, const int* __restrict__ bflag)
{
    GEMM_CORE(A, Wbase, 512, m0, n0)
    const int bf = bflag[0];
    const int region = roff + (nt >> 2);
    const void* bptr = region == 0 ? bq : (region == 1 ? bk : bv);
#pragma unroll
    for (int i = 0; i < 4; ++i) {
        const int row = m0 + wr * 64 + i * 16 + quad * 4;
#pragma unroll
        for (int j = 0; j < 4; ++j) {
            const int col = n0 + wc * 64 + j * 16 + l16;
            const int colr = col & 511;
            const float bvv = ldmix(bptr, colr, bf);
#pragma unroll
            for (int r = 0; r < 4; ++r) {
                const int rr = row + r;
                float c = acc[i][j][r] + bvv;
                if (region == 0) {
                    qout[(size_t)rr * 512 + colr] = __float2bfloat16(c * 0.125f);
                } else if (region == 1) {
                    kout[(size_t)rr * 512 + colr] = __float2bfloat16(c);
                } else {
                    const int b = rr >> 10, key = rr & 1023;
                    vtout[((size_t)(b * 512 + colr) << 10) | key] = __float2bfloat16(c);
                }
            }
        }
    }
}

// ---------------- MFMA flash attention, fixed-max softmax ----------------
// 1-D grid 1024: xcd=lin&7 owns 8 heads; all 16 q-tiles of a head on one XCD.
__global__ __launch_bounds__(256)
void mfattn_k(const bf16* __restrict__ Q, const bf16* __restrict__ Kb,
              const bf16* __restrict__ Vt, const float* __restrict__ maskf,
              bf16* __restrict__ O)
{
    const int lin = blockIdx.x;
    const int j = lin >> 3, xcd = lin & 7;
    const int head = xcd * 8 + (j >> 4);
    const int qt = j & 15;
    const int b = head >> 3, h = head & 7, s0 = qt * 64;
    const int tid = threadIdx.x;
    const int lane = tid & 63, w = tid >> 6;
    const int l16 = lane & 15, quad = lane >> 4;
    const int bS = b * S_, hc = h * DK_;
    const size_t vtb = (size_t)(b * H_ + h) * (DK_ * S_);

    __shared__ bf16 QPs[64 * 72];  // Q tile, then reused as P tile
    __shared__ bf16 Ks[64 * 72];
    __shared__ bf16 Vs[64 * 72];   // [dk][key]

    const int str = tid >> 3;
    const int stc = (tid & 7) * 8;

    *(uint4*)&QPs[str * 72 + stc]        = *(const uint4*)&Q[(size_t)(bS + s0 + str) * D_ + hc + stc];
    *(uint4*)&QPs[(str + 32) * 72 + stc] = *(const uint4*)&Q[(size_t)(bS + s0 + str + 32) * D_ + hc + stc];
    __syncthreads();

    const bf16x8 aq0 = *(const bf16x8*)&QPs[(w * 16 + l16) * 72 + quad * 8];
    const bf16x8 aq1 = *(const bf16x8*)&QPs[(w * 16 + l16) * 72 + quad * 8 + 32];

    f32x4 acc_o[4];
#pragma unroll
    for (int nb = 0; nb < 4; ++nb) acc_o[nb] = (f32x4){0.f, 0.f, 0.f, 0.f};
    float lrow[4] = {0.f, 0.f, 0.f, 0.f};

    for (int t0 = 0; t0 < S_; t0 += 64) {
        __syncthreads();
        *(uint4*)&Ks[str * 72 + stc]        = *(const uint4*)&Kb[(size_t)(bS + t0 + str) * D_ + hc + stc];
        *(uint4*)&Ks[(str + 32) * 72 + stc] = *(const uint4*)&Kb[(size_t)(bS + t0 + str + 32) * D_ + hc + stc];
        *(uint4*)&Vs[str * 72 + stc]        = *(const uint4*)&Vt[vtb + (size_t)str * S_ + t0 + stc];
        *(uint4*)&Vs[(str + 32) * 72 + stc] = *(const uint4*)&Vt[vtb + (size_t)(str + 32) * S_ + t0 + stc];
        __syncthreads();

        f32x4 sacc[4];
#pragma unroll
        for (int nb = 0; nb < 4; ++nb) sacc[nb] = (f32x4){0.f, 0.f, 0.f, 0.f};
#pragma unroll
        for (int nb = 0; nb < 4; ++nb) {
            const bf16x8 b0 = *(const bf16x8*)&Ks[(nb * 16 + l16) * 72 + quad * 8];
            const bf16x8 b1 = *(const bf16x8*)&Ks[(nb * 16 + l16) * 72 + quad * 8 + 32];
            sacc[nb] = __builtin_amdgcn_mfma_f32_16x16x32_bf16(aq0, b0, sacc[nb], 0, 0, 0);
            sacc[nb] = __builtin_amdgcn_mfma_f32_16x16x32_bf16(aq1, b1, sacc[nb], 0, 0, 0);
        }

#pragma unroll
        for (int nb = 0; nb < 4; ++nb) {
            const float mv = maskf[bS + t0 + nb * 16 + l16];
#pragma unroll
            for (int r = 0; r < 4; ++r) {
                const float p = __expf(sacc[nb][r] + mv);
                lrow[r] += p;
                QPs[(w * 16 + quad * 4 + r) * 72 + nb * 16 + l16] = __float2bfloat16(p);
            }
        }

        const bf16x8 ap0 = *(const bf16x8*)&QPs[(w * 16 + l16) * 72 + quad * 8];
        const bf16x8 ap1 = *(const bf16x8*)&QPs[(w * 16 + l16) * 72 + quad * 8 + 32];
#pragma unroll
        for (int nb = 0; nb < 4; ++nb) {
            const bf16x8 v0 = *(const bf16x8*)&Vs[(nb * 16 + l16) * 72 + quad * 8];
            const bf16x8 v1 = *(const bf16x8*)&Vs[(nb * 16 + l16) * 72 + quad * 8 + 32];
            acc_o[nb] = __builtin_amdgcn_mfma_f32_16x16x32_bf16(ap0, v0, acc_o[nb], 0, 0, 0);
            acc_o[nb] = __builtin_amdgcn_mfma_f32_16x16x32_bf16(ap1, v1, acc_o[nb], 0, 0, 0);
        }
    }

#pragma unroll
    for (int r = 0; r < 4; ++r) {
        float ls = lrow[r];
#pragma unroll
        for (int off = 8; off; off >>= 1) ls += __shfl_xor(ls, off);
        const float invl = 1.0f / ls;
        const size_t row = (size_t)(bS + s0 + w * 16 + quad * 4 + r) * D_;
#pragma unroll
        for (int nb = 0; nb < 4; ++nb)
            O[row + hc + nb * 16 + l16] = __float2bfloat16(acc_o[nb][r] * invl);
    }
}

// ---------------- LayerNorm over [S,D] per batch (fp32 Z) ----------------
__global__ __launch_bounds__(256)
void ln_reduce_k(const float* __restrict__ Z, float* __restrict__ stats)
{
    const int b = blockIdx.x >> 7;
    const int chunk = blockIdx.x & 127;
    const float4* p = (const float4*)(Z + (size_t)b * (S_ * D_) + (size_t)chunk * 4096);
    float s = 0.f, s2 = 0.f;
    for (int i = threadIdx.x; i < 1024; i += 256) {
        float4 v = p[i];
        s += v.x + v.y + v.z + v.w;
        s2 += v.x * v.x + v.y * v.y + v.z * v.z + v.w * v.w;
    }
#pragma unroll
    for (int off = 32; off; off >>= 1) { s += __shfl_xor(s, off); s2 += __shfl_xor(s2, off); }
    __shared__ float red[8];
    const int w = threadIdx.x >> 6, l = threadIdx.x & 63;
    if (l == 0) { red[w * 2] = s; red[w * 2 + 1] = s2; }
    __syncthreads();
    if (threadIdx.x == 0) {
        atomicAdd(&stats[b * 2],     red[0] + red[2] + red[4] + red[6]);
        atomicAdd(&stats[b * 2 + 1], red[1] + red[3] + red[5] + red[7]);
    }
}

template <bool FINAL>
__global__ __launch_bounds__(256)
void ln_apply_k(const float* __restrict__ Z, const float* __restrict__ stats,
                const void* __restrict__ w, const void* __restrict__ bb,
                bf16* __restrict__ outb, void* __restrict__ out_final,
                const int* __restrict__ flag)
{
    const int f = flag[0];
    const int b = blockIdx.y;
    const int i4 = (blockIdx.x * 256 + threadIdx.x) * 4;
    const float n = (float)(S_ * D_);
    const float m = stats[b * 2] / n;
    const float var = stats[b * 2 + 1] / n - m * m;
    const float inv = rsqrtf(var + 1e-6f);
    const size_t g = (size_t)b * (S_ * D_) + i4;
    const float4 z = *(const float4*)&Z[g];
    float v[4];
    v[0] = (z.x - m) * inv * ldmix(w, i4 + 0, f) + ldmix(bb, i4 + 0, f);
    v[1] = (z.y - m) * inv * ldmix(w, i4 + 1, f) + ldmix(bb, i4 + 1, f);
    v[2] = (z.z - m) * inv * ldmix(w, i4 + 2, f) + ldmix(bb, i4 + 2, f);
    v[3] = (z.w - m) * inv * ldmix(w, i4 + 3, f) + ldmix(bb, i4 + 3, f);
    union { ushort4 u4; unsigned short u[4]; } ov;
#pragma unroll
    for (int k = 0; k < 4; ++k) {
        bf16 t = __float2bfloat16(v[k]);
        __builtin_memcpy(&ov.u[k], &t, 2);
    }
    if constexpr (FINAL) {
        if (f) *(ushort4*)&((bf16*)out_final)[g] = ov.u4;
        else   *(float4*)&((float*)out_final)[g] = make_float4(v[0], v[1], v[2], v[3]);
    } else {
        *(ushort4*)&outb[g] = ov.u4;
    }
}

// ---------------- orchestration ----------------
extern "C" void kernel_launch(void* const* d_in, const int* in_sizes, int n_in,
                              void* d_out, int out_size, void* d_ws, size_t ws_size,
                              hipStream_t stream)
{
    (void)in_sizes; (void)n_in; (void)out_size; (void)ws_size;

    const void* x        = d_in[0];
    const void* y        = d_in[1];
    const int*  src_mask = (const int*) d_in[2];
    const int*  trg_mask = (const int*) d_in[3];
    const void* m1_wq = d_in[4];
    const void* m1_bq = d_in[5];
    const void* m1_wk = d_in[6];
    const void* m1_bk = d_in[7];
    const void* m1_wv = d_in[8];
    const void* m1_bv = d_in[9];
    const void* m1_wo = d_in[10];
    const void* m1_bo = d_in[11];
    const void* m2_wq = d_in[12];
    const void* m2_bq = d_in[13];
    const void* m2_wk = d_in[14];
    const void* m2_bk = d_in[15];
    const void* m2_wv = d_in[16];
    const void* m2_bv = d_in[17];
    const void* m2_wo = d_in[18];
    const void* m2_bo = d_in[19];
    const void* pw1   = d_in[20];
    const void* pb1   = d_in[21];
    const void* pw2   = d_in[22];
    const void* pb2   = d_in[23];
    const void* ln1_w = d_in[24];
    const void* ln1_b = d_in[25];
    const void* ln2_w = d_in[26];
    const void* ln2_b = d_in[27];
    const void* ln3_w = d_in[28];
    const void* ln3_b = d_in[29];

    const size_t NACT = (size_t)8192 * 512;

    float* zb    = (float*)d_ws;
    float* stats = zb + NACT;
    int*   flag  = (int*)(stats + 48);
    float* trgf  = stats + 64;
    float* srcf  = trgf + 8192;
    bf16* xb16 = (bf16*)(srcf + 8192);
    bf16* yb16 = xb16 + NACT;
    bf16* qb   = yb16 + NACT;
    bf16* kb   = qb   + NACT;
    bf16* vbT  = kb   + NACT;
    bf16* aob  = vbT  + NACT;
    bf16* x1b  = aob  + NACT;
    bf16* x2b  = x1b  + NACT;
    bf16* ffb  = x2b  + NACT;
    bf16* Wq1r = ffb  + (size_t)8192 * 2048;
    bf16* Wq2r = Wq1r + 3 * 262144;
    bf16* Wo1b = Wq1r + 6 * 262144;
    bf16* Wo2b = Wo1b + 262144;
    bf16* W1b  = Wo2b + 262144;
    bf16* W2b  = W1b  + 1048576;

    detect_k<<<1, 64, 0, stream>>>((const unsigned short*)x, stats, flag);
    maskf_k<<<64, 256, 0, stream>>>(trg_mask, src_mask, trgf, srcf);
    convxy_k<<<32768, 256, 0, stream>>>(x, y, xb16, yb16, flag);
    repack6_k<<<6144, 256, 0, stream>>>(m1_wq, m1_wk, m1_wv, m2_wq, m2_wk, m2_wv, Wq1r, flag);
    convw4_k<<<10240, 256, 0, stream>>>(m1_wo, m2_wo, pw1, pw2, Wo1b, flag);

    const dim3 blk(256);
    const dim3 gln(512, B_);

    // ---- self-attention ----
    mgemm_qkv_k<<<dim3(12 * 64), blk, 0, stream>>>(xb16, Wq1r, m1_bq, m1_bk, m1_bv, qb, kb, vbT, 12, 0, flag);
    mfattn_k<<<dim3(1024), blk, 0, stream>>>(qb, kb, vbT, trgf, aob);
    mgemm_k<true, false, float><<<dim3(4 * 64), blk, 0, stream>>>(aob, Wo1b, m1_bo, x, zb, 512, 512, 4, flag, flag);
    ln_reduce_k<<<1024, blk, 0, stream>>>(zb, stats);
    ln_apply_k<false><<<gln, blk, 0, stream>>>(zb, stats, ln1_w, ln1_b, x1b, nullptr, flag);

    // ---- cross-attention ----
    mgemm_qkv_k<<<dim3(4 * 64), blk, 0, stream>>>(x1b, Wq2r, m2_bq, m2_bk, m2_bv, qb, kb, vbT, 4, 0, flag);
    mgemm_qkv_k<<<dim3(8 * 64), blk, 0, stream>>>(yb16, Wq2r + 262144, m2_bq, m2_bk, m2_bv, qb, kb, vbT, 8, 1, flag);
    mfattn_k<<<dim3(1024), blk, 0, stream>>>(qb, kb, vbT, srcf, aob);
    mgemm_k<true, false, float><<<dim3(4 * 64), blk, 0, stream>>>(aob, Wo2b, m2_bo, x1b, zb, 512, 512, 4, flag, flag + 1);
    ln_reduce_k<<<1024, blk, 0, stream>>>(zb, stats + 16);
    ln_apply_k<false><<<gln, blk, 0, stream>>>(zb, stats + 16, ln2_w, ln2_b, x2b, nullptr, flag);

    // ---- FFN ----
    mgemm_k<false, true, bf16><<<dim3(16 * 64), blk, 0, stream>>>(x2b, W1b, pb1, nullptr, ffb, 2048, 512, 16, flag, flag);
    mgemm_k<true, false, float><<<dim3(4 * 64), blk, 0, stream>>>(ffb, W2b, pb2, x2b, zb, 512, 2048, 4, flag, flag + 1);
    ln_reduce_k<<<1024, blk, 0, stream>>>(zb, stats + 32);
    ln_apply_k<true><<<gln, blk, 0, stream>>>(zb, stats + 32, ln3_w, ln3_b, nullptr, d_out, flag);
}

// Round 9
// 524.258 us; speedup vs baseline: 9.7837x; 1.1885x over previous
//
#include <hip/hip_runtime.h>
#include <hip/hip_bf16.h>

#define B_   8
#define S_   1024
#define D_   512
#define H_   8
#define DK_  64
#define DFF_ 2048

typedef __hip_bfloat16 bf16;
typedef __attribute__((ext_vector_type(8))) short bf16x8;
typedef __attribute__((ext_vector_type(4))) float f32x4;

// flag==1 -> bf16 data; flag==0 -> fp32 data
__device__ __forceinline__ float ldmix(const void* p, size_t i, int f) {
    return f ? __bfloat162float(((const bf16*)p)[i]) : ((const float*)p)[i];
}
__device__ __forceinline__ void store_o(float* p, float v) { *p = v; }
__device__ __forceinline__ void store_o(bf16* p, float v)  { *p = __float2bfloat16(v); }

// async global->LDS, 16B per lane; lds base wave-uniform (lane*16 implicit)
__device__ __forceinline__ void gl_lds16(const void* g, void* l) {
    __builtin_amdgcn_global_load_lds(
        (const __attribute__((address_space(1))) unsigned int*)g,
        (__attribute__((address_space(3))) unsigned int*)l, 16, 0, 0);
}

// ---------------- detect dtype + zero LN stats + constants ----------------
__global__ __launch_bounds__(64) void detect_k(const unsigned short* __restrict__ x,
                                               float* __restrict__ stats,
                                               int* __restrict__ flag)
{
    if (threadIdx.x < 48) stats[threadIdx.x] = 0.f;
    int cnt = 0;
    for (int i = threadIdx.x; i < 4096; i += 64) {
        int e = (x[i] >> 7) & 0xFF;
        if (e >= 0xC0) cnt++;
    }
#pragma unroll
    for (int off = 32; off; off >>= 1) cnt += __shfl_xor(cnt, off);
    if (threadIdx.x == 0) { flag[0] = (cnt > 16) ? 0 : 1; flag[1] = 1; }
}

// ---------------- masks -> additive float ----------------
__global__ __launch_bounds__(256) void maskf_k(const int* __restrict__ trg,
                                               const int* __restrict__ src,
                                               float* __restrict__ trgf,
                                               float* __restrict__ srcf)
{
    int i = blockIdx.x * 256 + threadIdx.x;
    if (i < 8192) trgf[i] = trg[i] ? 0.f : -1.0e10f;
    else          srcf[i - 8192] = src[i - 8192] ? 0.f : -1.0e10f;
}

// ---------------- x,y -> bf16 (8 elems/thread; pure copy when already bf16) ----------------
__global__ __launch_bounds__(256) void convxy_k(const void* __restrict__ x,
                                                const void* __restrict__ y,
                                                bf16* __restrict__ xb, bf16* __restrict__ yb,
                                                const int* __restrict__ flag)
{
    const int f = flag[0];
    const int N8 = 8192 * 512 / 8;   // 524288
    int i = blockIdx.x * 256 + threadIdx.x;
    const void* src; bf16* dst; size_t base;
    if (i < N8) { src = x; dst = xb; base = (size_t)i * 8; }
    else        { src = y; dst = yb; base = (size_t)(i - N8) * 8; }
    if (f) {
        *(uint4*)(dst + base) = *(const uint4*)((const bf16*)src + base);
    } else {
        const float4 a = *(const float4*)((const float*)src + base);
        const float4 b = *(const float4*)((const float*)src + base + 4);
        bf16 o[8] = {__float2bfloat16(a.x), __float2bfloat16(a.y),
                     __float2bfloat16(a.z), __float2bfloat16(a.w),
                     __float2bfloat16(b.x), __float2bfloat16(b.y),
                     __float2bfloat16(b.z), __float2bfloat16(b.w)};
        *(uint4*)(dst + base) = *(uint4*)o;
    }
}

// ---------------- 6 qkv weight repacks: in[h,d,k] -> out[(h*64+k), d] ----------------
__global__ __launch_bounds__(256) void repack6_k(const void* __restrict__ w0, const void* __restrict__ w1,
                                                 const void* __restrict__ w2, const void* __restrict__ w3,
                                                 const void* __restrict__ w4, const void* __restrict__ w5,
                                                 bf16* __restrict__ out, const int* __restrict__ flag)
{
    const int f = flag[0];
    const int widx = blockIdx.x >> 10;
    const int j = ((blockIdx.x & 1023) << 8) + threadIdx.x;
    const void* in = widx == 0 ? w0 : widx == 1 ? w1 : widx == 2 ? w2
                   : widx == 3 ? w3 : widx == 4 ? w4 : w5;
    int n = j >> 9, d = j & 511;
    int h = n >> 6, k = n & 63;
    out[(size_t)widx * 262144 + j] =
        __float2bfloat16(ldmix(in, (size_t)h * (D_ * DK_) + (size_t)d * DK_ + k, f));
}

// ---------------- 4 [N][K] weight converts (8 elems/thread) ----------------
__global__ __launch_bounds__(256) void convw4_k(const void* __restrict__ wo1, const void* __restrict__ wo2,
                                                const void* __restrict__ pw1, const void* __restrict__ pw2,
                                                bf16* __restrict__ out, const int* __restrict__ flag)
{
    const int f = flag[0];
    const size_t i8 = (size_t)(blockIdx.x * 256 + threadIdx.x) * 8;   // < 2621440
    const void* in; size_t off;
    if (i8 < 262144)       { in = wo1; off = 0; }
    else if (i8 < 524288)  { in = wo2; off = 262144; }
    else if (i8 < 1572864) { in = pw1; off = 524288; }
    else                   { in = pw2; off = 1572864; }
    const size_t s = i8 - off;
    if (f) {
        *(uint4*)(out + i8) = *(const uint4*)((const bf16*)in + s);
    } else {
        const float4 a = *(const float4*)((const float*)in + s);
        const float4 b = *(const float4*)((const float*)in + s + 4);
        bf16 o[8] = {__float2bfloat16(a.x), __float2bfloat16(a.y),
                     __float2bfloat16(a.z), __float2bfloat16(a.w),
                     __float2bfloat16(b.x), __float2bfloat16(b.y),
                     __float2bfloat16(b.z), __float2bfloat16(b.w)};
        *(uint4*)(out + i8) = *(uint4*)o;
    }
}

// ==================== MFMA GEMM core (templated BN = NB*32) ====================
// BM=128, BK=32; 4 waves 2x2; wave tile 64 x (NB*16). global_load_lds 16B staging,
// XOR-swizzled LDS (granule q = g ^ ((row>>1)&3)), 0 bank conflicts (R8-verified).
template <int NB>
__device__ __forceinline__ void gemm_core(const bf16* __restrict__ A, const bf16* __restrict__ Wt,
                                          int K, int m0, int n0, bf16* As, bf16* Bs,
                                          f32x4 (&acc)[4][NB])
{
    const int tid = threadIdx.x;
    const int lane = tid & 63, w = tid >> 6;
    const int wr = w >> 1, wc = w & 1;
    const int l16 = lane & 15, quad = lane >> 4;
    const int r0 = tid >> 2;
    const int g0 = (tid & 3) ^ ((r0 >> 1) & 3);
    const bf16* pa0 = A + (size_t)(m0 + r0) * K + g0 * 8;
    const bf16* pa1 = pa0 + (size_t)64 * K;
    const bf16* pb0 = Wt + (size_t)(n0 + r0) * K + g0 * 8;
    const bf16* pb1 = pb0 + (size_t)64 * K;
    bf16* lA0 = As + w * 512;
    bf16* lA1 = As + 2048 + w * 512;
    bf16* lB0 = Bs + w * 512;
    bf16* lB1 = Bs + 2048 + w * 512;

    int aoff[4], boff[NB];
#pragma unroll
    for (int i = 0; i < 4; ++i) {
        const int ra = wr * 64 + i * 16 + l16;
        aoff[i] = ra * 32 + (quad ^ ((ra >> 1) & 3)) * 8;
    }
#pragma unroll
    for (int j = 0; j < NB; ++j) {
        const int rb = wc * (NB * 16) + j * 16 + l16;
        boff[j] = rb * 32 + (quad ^ ((rb >> 1) & 3)) * 8;
    }

    for (int k0 = 0; k0 < K; k0 += 32) {
        __syncthreads();
        gl_lds16(pa0 + k0, lA0);
        gl_lds16(pa1 + k0, lA1);
        gl_lds16(pb0 + k0, lB0);
        if constexpr (NB == 4) gl_lds16(pb1 + k0, lB1);
        __syncthreads();
        bf16x8 af[4], bg[NB];
#pragma unroll
        for (int i = 0; i < 4; ++i) af[i] = *(const bf16x8*)&As[aoff[i]];
#pragma unroll
        for (int j = 0; j < NB; ++j) bg[j] = *(const bf16x8*)&Bs[boff[j]];
#pragma unroll
        for (int i = 0; i < 4; ++i)
#pragma unroll
            for (int j = 0; j < NB; ++j)
                acc[i][j] = __builtin_amdgcn_mfma_f32_16x16x32_bf16(af[i], bg[j], acc[i][j], 0, 0, 0);
    }
}

// standard GEMM: C[M,N] = A @ Wt^T + bias (+relu) (+res) (+LN-stats)
// 1-D grid, XCD-stripe mapping: xcd=lin&7 owns an 8-M-tile stripe, N fastest.
template <int NB, bool HAS_RES, bool RELU, bool STATS, typename OutT>
__global__ __launch_bounds__(256)
void mgemm_k(const bf16* __restrict__ A, const bf16* __restrict__ Wt,
             const void* __restrict__ bias, const void* __restrict__ res,
             OutT* __restrict__ C, int N, int K, int Gx,
             const int* __restrict__ bflag, const int* __restrict__ rflag,
             float* __restrict__ stats)
{
    __shared__ bf16 As[4096];
    __shared__ bf16 Bs[NB * 1024];
    const int lin = blockIdx.x;
    const int mt = (lin & 7) * 8 + (lin >> 3) / Gx;
    const int nt = (lin >> 3) % Gx;
    const int m0 = mt * 128, n0 = nt * (NB * 32);

    f32x4 acc[4][NB];
#pragma unroll
    for (int i = 0; i < 4; ++i)
#pragma unroll
        for (int j = 0; j < NB; ++j) acc[i][j] = (f32x4){0.f, 0.f, 0.f, 0.f};

    gemm_core<NB>(A, Wt, K, m0, n0, As, Bs, acc);

    const int tid = threadIdx.x;
    const int lane = tid & 63, w = tid >> 6;
    const int wr = w >> 1, wc = w & 1;
    const int l16 = lane & 15, quad = lane >> 4;
    const int bf = bflag[0];
    int rf = 0;
    if constexpr (HAS_RES) rf = rflag[0];

    float s = 0.f, s2 = 0.f;
#pragma unroll
    for (int i = 0; i < 4; ++i) {
        const int row = m0 + wr * 64 + i * 16 + quad * 4;
#pragma unroll
        for (int j = 0; j < NB; ++j) {
            const int col = n0 + wc * (NB * 16) + j * 16 + l16;
            const float bv = ldmix(bias, col, bf);
#pragma unroll
            for (int r = 0; r < 4; ++r) {
                float c = acc[i][j][r] + bv;
                if constexpr (RELU) c = fmaxf(c, 0.f);
                if constexpr (HAS_RES) c += ldmix(res, (size_t)(row + r) * N + col, rf);
                if constexpr (STATS) { s += c; s2 += c * c; }
                store_o(&C[(size_t)(row + r) * N + col], c);
            }
        }
    }
    if constexpr (STATS) {
#pragma unroll
        for (int off = 32; off; off >>= 1) { s += __shfl_xor(s, off); s2 += __shfl_xor(s2, off); }
        __syncthreads();                     // all waves done with As
        float* red = (float*)As;
        if (lane == 0) { red[w * 2] = s; red[w * 2 + 1] = s2; }
        __syncthreads();
        if (tid == 0) {
            const int b = m0 >> 10;
            atomicAdd(&stats[b * 2],     red[0] + red[2] + red[4] + red[6]);
            atomicAdd(&stats[b * 2 + 1], red[1] + red[3] + red[5] + red[7]);
        }
    }
}

// fused projection GEMM: routes Q (x0.125) / K / V(transposed) by 512-col region
template <int NB, int RSHIFT>
__global__ __launch_bounds__(256)
void mgemm_qkv_k(const bf16* __restrict__ A, const bf16* __restrict__ Wbase,
                 const void* __restrict__ bq, const void* __restrict__ bk, const void* __restrict__ bv,
                 bf16* __restrict__ qout, bf16* __restrict__ kout, bf16* __restrict__ vtout,
                 int Gx, int roff, const int* __restrict__ bflag)
{
    __shared__ bf16 As[4096];
    __shared__ bf16 Bs[NB * 1024];
    const int lin = blockIdx.x;
    const int mt = (lin & 7) * 8 + (lin >> 3) / Gx;
    const int nt = (lin >> 3) % Gx;
    const int m0 = mt * 128, n0 = nt * (NB * 32);

    f32x4 acc[4][NB];
#pragma unroll
    for (int i = 0; i < 4; ++i)
#pragma unroll
        for (int j = 0; j < NB; ++j) acc[i][j] = (f32x4){0.f, 0.f, 0.f, 0.f};

    gemm_core<NB>(A, Wbase, 512, m0, n0, As, Bs, acc);

    const int tid = threadIdx.x;
    const int lane = tid & 63, w = tid >> 6;
    const int wr = w >> 1, wc = w & 1;
    const int l16 = lane & 15, quad = lane >> 4;
    const int bf = bflag[0];
    const int region = roff + (nt >> RSHIFT);
    const void* bptr = region == 0 ? bq : (region == 1 ? bk : bv);

#pragma unroll
    for (int i = 0; i < 4; ++i) {
        const int row = m0 + wr * 64 + i * 16 + quad * 4;
#pragma unroll
        for (int j = 0; j < NB; ++j) {
            const int col = n0 + wc * (NB * 16) + j * 16 + l16;
            const int colr = col & 511;
            const float bvv = ldmix(bptr, colr, bf);
#pragma unroll
            for (int r = 0; r < 4; ++r) {
                const int rr = row + r;
                float c = acc[i][j][r] + bvv;
                if (region == 0) {
                    qout[(size_t)rr * 512 + colr] = __float2bfloat16(c * 0.125f);
                } else if (region == 1) {
                    kout[(size_t)rr * 512 + colr] = __float2bfloat16(c);
                } else {
                    const int b = rr >> 10, key = rr & 1023;
                    vtout[((size_t)(b * 512 + colr) << 10) | key] = __float2bfloat16(c);
                }
            }
        }
    }
}

// ---------------- MFMA flash attention, fixed-max softmax ----------------
// 1-D grid 1024: xcd=lin&7 owns 8 heads; all 16 q-tiles of a head on one XCD.
__global__ __launch_bounds__(256)
void mfattn_k(const bf16* __restrict__ Q, const bf16* __restrict__ Kb,
              const bf16* __restrict__ Vt, const float* __restrict__ maskf,
              bf16* __restrict__ O)
{
    const int lin = blockIdx.x;
    const int j = lin >> 3, xcd = lin & 7;
    const int head = xcd * 8 + (j >> 4);
    const int qt = j & 15;
    const int b = head >> 3, h = head & 7, s0 = qt * 64;
    const int tid = threadIdx.x;
    const int lane = tid & 63, w = tid >> 6;
    const int l16 = lane & 15, quad = lane >> 4;
    const int bS = b * S_, hc = h * DK_;
    const size_t vtb = (size_t)(b * H_ + h) * (DK_ * S_);

    __shared__ bf16 QPs[64 * 72];
    __shared__ bf16 Ks[64 * 72];
    __shared__ bf16 Vs[64 * 72];

    const int str = tid >> 3;
    const int stc = (tid & 7) * 8;

    *(uint4*)&QPs[str * 72 + stc]        = *(const uint4*)&Q[(size_t)(bS + s0 + str) * D_ + hc + stc];
    *(uint4*)&QPs[(str + 32) * 72 + stc] = *(const uint4*)&Q[(size_t)(bS + s0 + str + 32) * D_ + hc + stc];
    __syncthreads();

    const bf16x8 aq0 = *(const bf16x8*)&QPs[(w * 16 + l16) * 72 + quad * 8];
    const bf16x8 aq1 = *(const bf16x8*)&QPs[(w * 16 + l16) * 72 + quad * 8 + 32];

    f32x4 acc_o[4];
#pragma unroll
    for (int nb = 0; nb < 4; ++nb) acc_o[nb] = (f32x4){0.f, 0.f, 0.f, 0.f};
    float lrow[4] = {0.f, 0.f, 0.f, 0.f};

    for (int t0 = 0; t0 < S_; t0 += 64) {
        __syncthreads();
        *(uint4*)&Ks[str * 72 + stc]        = *(const uint4*)&Kb[(size_t)(bS + t0 + str) * D_ + hc + stc];
        *(uint4*)&Ks[(str + 32) * 72 + stc] = *(const uint4*)&Kb[(size_t)(bS + t0 + str + 32) * D_ + hc + stc];
        *(uint4*)&Vs[str * 72 + stc]        = *(const uint4*)&Vt[vtb + (size_t)str * S_ + t0 + stc];
        *(uint4*)&Vs[(str + 32) * 72 + stc] = *(const uint4*)&Vt[vtb + (size_t)(str + 32) * S_ + t0 + stc];
        __syncthreads();

        f32x4 sacc[4];
#pragma unroll
        for (int nb = 0; nb < 4; ++nb) sacc[nb] = (f32x4){0.f, 0.f, 0.f, 0.f};
#pragma unroll
        for (int nb = 0; nb < 4; ++nb) {
            const bf16x8 b0 = *(const bf16x8*)&Ks[(nb * 16 + l16) * 72 + quad * 8];
            const bf16x8 b1 = *(const bf16x8*)&Ks[(nb * 16 + l16) * 72 + quad * 8 + 32];
            sacc[nb] = __builtin_amdgcn_mfma_f32_16x16x32_bf16(aq0, b0, sacc[nb], 0, 0, 0);
            sacc[nb] = __builtin_amdgcn_mfma_f32_16x16x32_bf16(aq1, b1, sacc[nb], 0, 0, 0);
        }

#pragma unroll
        for (int nb = 0; nb < 4; ++nb) {
            const float mv = maskf[bS + t0 + nb * 16 + l16];
#pragma unroll
            for (int r = 0; r < 4; ++r) {
                const float p = __expf(sacc[nb][r] + mv);
                lrow[r] += p;
                QPs[(w * 16 + quad * 4 + r) * 72 + nb * 16 + l16] = __float2bfloat16(p);
            }
        }

        const bf16x8 ap0 = *(const bf16x8*)&QPs[(w * 16 + l16) * 72 + quad * 8];
        const bf16x8 ap1 = *(const bf16x8*)&QPs[(w * 16 + l16) * 72 + quad * 8 + 32];
#pragma unroll
        for (int nb = 0; nb < 4; ++nb) {
            const bf16x8 v0 = *(const bf16x8*)&Vs[(nb * 16 + l16) * 72 + quad * 8];
            const bf16x8 v1 = *(const bf16x8*)&Vs[(nb * 16 + l16) * 72 + quad * 8 + 32];
            acc_o[nb] = __builtin_amdgcn_mfma_f32_16x16x32_bf16(ap0, v0, acc_o[nb], 0, 0, 0);
            acc_o[nb] = __builtin_amdgcn_mfma_f32_16x16x32_bf16(ap1, v1, acc_o[nb], 0, 0, 0);
        }
    }

#pragma unroll
    for (int r = 0; r < 4; ++r) {
        float ls = lrow[r];
#pragma unroll
        for (int off = 8; off; off >>= 1) ls += __shfl_xor(ls, off);
        const float invl = 1.0f / ls;
        const size_t row = (size_t)(bS + s0 + w * 16 + quad * 4 + r) * D_;
#pragma unroll
        for (int nb = 0; nb < 4; ++nb)
            O[row + hc + nb * 16 + l16] = __float2bfloat16(acc_o[nb][r] * invl);
    }
}

// ---------------- LayerNorm apply (stats already accumulated by GEMM epilogues) ----------------
template <bool FINAL>
__global__ __launch_bounds__(256)
void ln_apply_k(const float* __restrict__ Z, const float* __restrict__ stats,
                const void* __restrict__ w, const void* __restrict__ bb,
                bf16* __restrict__ outb, void* __restrict__ out_final,
                const int* __restrict__ flag)
{
    const int f = flag[0];
    const int b = blockIdx.y;
    const int i4 = (blockIdx.x * 256 + threadIdx.x) * 4;
    const float n = (float)(S_ * D_);
    const float m = stats[b * 2] / n;
    const float var = stats[b * 2 + 1] / n - m * m;
    const float inv = rsqrtf(var + 1e-6f);
    const size_t g = (size_t)b * (S_ * D_) + i4;
    const float4 z = *(const float4*)&Z[g];
    float v[4];
    v[0] = (z.x - m) * inv * ldmix(w, i4 + 0, f) + ldmix(bb, i4 + 0, f);
    v[1] = (z.y - m) * inv * ldmix(w, i4 + 1, f) + ldmix(bb, i4 + 1, f);
    v[2] = (z.z - m) * inv * ldmix(w, i4 + 2, f) + ldmix(bb, i4 + 2, f);
    v[3] = (z.w - m) * inv * ldmix(w, i4 + 3, f) + ldmix(bb, i4 + 3, f);
    union { ushort4 u4; unsigned short u[4]; } ov;
#pragma unroll
    for (int k = 0; k < 4; ++k) {
        bf16 t = __float2bfloat16(v[k]);
        __builtin_memcpy(&ov.u[k], &t, 2);
    }
    if constexpr (FINAL) {
        if (f) *(ushort4*)&((bf16*)out_final)[g] = ov.u4;
        else   *(float4*)&((float*)out_final)[g] = make_float4(v[0], v[1], v[2], v[3]);
    } else {
        *(ushort4*)&outb[g] = ov.u4;
    }
}

// ---------------- orchestration ----------------
extern "C" void kernel_launch(void* const* d_in, const int* in_sizes, int n_in,
                              void* d_out, int out_size, void* d_ws, size_t ws_size,
                              hipStream_t stream)
{
    (void)in_sizes; (void)n_in; (void)out_size; (void)ws_size;

    const void* x        = d_in[0];
    const void* y        = d_in[1];
    const int*  src_mask = (const int*) d_in[2];
    const int*  trg_mask = (const int*) d_in[3];
    const void* m1_wq = d_in[4];
    const void* m1_bq = d_in[5];
    const void* m1_wk = d_in[6];
    const void* m1_bk = d_in[7];
    const void* m1_wv = d_in[8];
    const void* m1_bv = d_in[9];
    const void* m1_wo = d_in[10];
    const void* m1_bo = d_in[11];
    const void* m2_wq = d_in[12];
    const void* m2_bq = d_in[13];
    const void* m2_wk = d_in[14];
    const void* m2_bk = d_in[15];
    const void* m2_wv = d_in[16];
    const void* m2_bv = d_in[17];
    const void* m2_wo = d_in[18];
    const void* m2_bo = d_in[19];
    const void* pw1   = d_in[20];
    const void* pb1   = d_in[21];
    const void* pw2   = d_in[22];
    const void* pb2   = d_in[23];
    const void* ln1_w = d_in[24];
    const void* ln1_b = d_in[25];
    const void* ln2_w = d_in[26];
    const void* ln2_b = d_in[27];
    const void* ln3_w = d_in[28];
    const void* ln3_b = d_in[29];

    const size_t NACT = (size_t)8192 * 512;

    float* zb    = (float*)d_ws;
    float* stats = zb + NACT;
    int*   flag  = (int*)(stats + 48);
    float* trgf  = stats + 64;
    float* srcf  = trgf + 8192;
    bf16* xb16 = (bf16*)(srcf + 8192);
    bf16* yb16 = xb16 + NACT;
    bf16* qb   = yb16 + NACT;
    bf16* kb   = qb   + NACT;
    bf16* vbT  = kb   + NACT;
    bf16* aob  = vbT  + NACT;
    bf16* x1b  = aob  + NACT;
    bf16* x2b  = x1b  + NACT;
    bf16* ffb  = x2b  + NACT;
    bf16* Wq1r = ffb  + (size_t)8192 * 2048;
    bf16* Wq2r = Wq1r + 3 * 262144;
    bf16* Wo1b = Wq1r + 6 * 262144;
    bf16* Wo2b = Wo1b + 262144;
    bf16* W1b  = Wo2b + 262144;
    bf16* W2b  = W1b  + 1048576;

    detect_k<<<1, 64, 0, stream>>>((const unsigned short*)x, stats, flag);
    maskf_k<<<64, 256, 0, stream>>>(trg_mask, src_mask, trgf, srcf);
    convxy_k<<<4096, 256, 0, stream>>>(x, y, xb16, yb16, flag);
    repack6_k<<<6144, 256, 0, stream>>>(m1_wq, m1_wk, m1_wv, m2_wq, m2_wk, m2_wv, Wq1r, flag);
    convw4_k<<<1280, 256, 0, stream>>>(m1_wo, m2_wo, pw1, pw2, Wo1b, flag);

    const dim3 blk(256);
    const dim3 gln(512, B_);

    // ---- self-attention ----
    mgemm_qkv_k<4, 2><<<dim3(12 * 64), blk, 0, stream>>>(xb16, Wq1r, m1_bq, m1_bk, m1_bv, qb, kb, vbT, 12, 0, flag);
    mfattn_k<<<dim3(1024), blk, 0, stream>>>(qb, kb, vbT, trgf, aob);
    mgemm_k<2, true, false, true, float><<<dim3(8 * 64), blk, 0, stream>>>(aob, Wo1b, m1_bo, x, zb, 512, 512, 8, flag, flag, stats);
    ln_apply_k<false><<<gln, blk, 0, stream>>>(zb, stats, ln1_w, ln1_b, x1b, nullptr, flag);

    // ---- cross-attention ----
    mgemm_qkv_k<2, 3><<<dim3(8 * 64), blk, 0, stream>>>(x1b, Wq2r, m2_bq, m2_bk, m2_bv, qb, kb, vbT, 8, 0, flag);
    mgemm_qkv_k<4, 2><<<dim3(8 * 64), blk, 0, stream>>>(yb16, Wq2r + 262144, m2_bq, m2_bk, m2_bv, qb, kb, vbT, 8, 1, flag);
    mfattn_k<<<dim3(1024), blk, 0, stream>>>(qb, kb, vbT, srcf, aob);
    mgemm_k<2, true, false, true, float><<<dim3(8 * 64), blk, 0, stream>>>(aob, Wo2b, m2_bo, x1b, zb, 512, 512, 8, flag, flag + 1, stats + 16);
    ln_apply_k<false><<<gln, blk, 0, stream>>>(zb, stats + 16, ln2_w, ln2_b, x2b, nullptr, flag);

    // ---- FFN ----
    mgemm_k<4, false, true, false, bf16><<<dim3(16 * 64), blk, 0, stream>>>(x2b, W1b, pb1, nullptr, ffb, 2048, 512, 16, flag, flag, nullptr);
    mgemm_k<2, true, false, true, float><<<dim3(8 * 64), blk, 0, stream>>>(ffb, W2b, pb2, x2b, zb, 512, 2048, 8, flag, flag + 1, stats + 32);
    ln_apply_k<true><<<gln, blk, 0, stream>>>(zb, stats + 32, ln3_w, ln3_b, nullptr, d_out, flag);
}